// Round 1
// baseline (618.588 us; speedup 1.0000x reference)
//
#include <hip/hip_runtime.h>
#include <stdint.h>

typedef unsigned short u16;
typedef unsigned int u32;
typedef __attribute__((ext_vector_type(8))) short short8;
typedef __attribute__((ext_vector_type(4))) float f32x4;

#define EMBED 1024
#define HEADS 16
#define HDIM 64
#define NBATCH 2
#define SLEN 64
#define RLEN 2048
#define TOTKV (SLEN + RLEN)   // 2112

// ---------- small helpers ----------
__device__ __forceinline__ float bf2f(u16 u) {
  union { u32 i; float f; } v; v.i = ((u32)u) << 16; return v.f;
}
__device__ __forceinline__ u16 f2bf(float f) {
  union { float f; u32 i; } v; v.f = f;
  return (u16)((v.i + 0x7fffu + ((v.i >> 16) & 1u)) >> 16);  // RNE
}
__device__ __forceinline__ void up2(u32 u, float& a, float& b) {
  union { u32 i; float f; } x, y;
  x.i = u << 16; y.i = u & 0xffff0000u;
  a = x.f; b = y.f;
}
__device__ __forceinline__ void gload16(const void* g, void* l) {
  __builtin_amdgcn_global_load_lds((const __attribute__((address_space(1))) u32*)g,
                                   (__attribute__((address_space(3))) u32*)l, 16, 0, 0);
}

// ---------- RoPE table: cos/sin(pos * 10000^(-i/32)) for pos in [0,2112), i in [0,32) ----------
__global__ void rope_table_k(float* __restrict__ cosT, float* __restrict__ sinT) {
  int idx = blockIdx.x * blockDim.x + threadIdx.x;
  if (idx >= TOTKV * 32) return;
  int pos = idx >> 5, i = idx & 31;
  float inv = powf(10000.0f, -(float)i / 32.0f);
  float a = (float)pos * inv;
  float s, c;
  sincosf(a, &s, &c);
  cosT[idx] = c; sinT[idx] = s;
}

// ---------- f32 -> bf16 convert (vectorized) ----------
__global__ void f2bf_k(const float* __restrict__ src, u16* __restrict__ dst, int n) {
  int i = (blockIdx.x * blockDim.x + threadIdx.x) * 4;
  if (i >= n) return;
  float4 v = *(const float4*)(src + i);
  u16 o0 = f2bf(v.x), o1 = f2bf(v.y), o2 = f2bf(v.z), o3 = f2bf(v.w);
  u32 lo = (u32)o0 | ((u32)o1 << 16);
  u32 hi = (u32)o2 | ((u32)o3 << 16);
  uint2 o; o.x = lo; o.y = hi;
  *(uint2*)(dst + i) = o;
}

// ---------- weight transpose: W[k][n] f32 -> Wt[n][k] bf16, 10 matrices ----------
struct WSrc { const float* p[10]; };
__global__ void transpose_w_k(WSrc wsrc, u16* __restrict__ dst) {
  __shared__ float tile[64][65];
  const float* src = wsrc.p[blockIdx.z];
  u16* out = dst + (size_t)blockIdx.z * (EMBED * (size_t)EMBED);
  int t = threadIdx.x;
  int k0 = blockIdx.y * 64, n0 = blockIdx.x * 64;
  int r0 = t >> 4, c0 = (t & 15) * 4;
#pragma unroll
  for (int i = 0; i < 4; ++i) {
    int r = i * 16 + r0;
    float4 v = *(const float4*)(src + (size_t)(k0 + r) * EMBED + n0 + c0);
    tile[r][c0] = v.x; tile[r][c0 + 1] = v.y; tile[r][c0 + 2] = v.z; tile[r][c0 + 3] = v.w;
  }
  __syncthreads();
#pragma unroll
  for (int i = 0; i < 4; ++i) {
    int n = i * 16 + r0;
    u16 o0 = f2bf(tile[c0][n]), o1 = f2bf(tile[c0 + 1][n]);
    u16 o2 = f2bf(tile[c0 + 2][n]), o3 = f2bf(tile[c0 + 3][n]);
    uint2 o; o.x = (u32)o0 | ((u32)o1 << 16); o.y = (u32)o2 | ((u32)o3 << 16);
    *(uint2*)(out + (size_t)(n0 + n) * EMBED + k0 + c0) = o;
  }
}

// ---------- bf16 GEMM: C[M x 1024] = A[M x 1024] @ Wt^T (+bias), m97-style ----------
// OUTMODE 0: bf16 head-split out (B,H,L,D), optional RoPE (z < nrope)
// OUTMODE 1: f32 row-major out [M x 1024]
template<int OUTMODE>
__global__ __launch_bounds__(256)
void gemm_k(const u16* __restrict__ A,
            const u16* W0, const u16* W1, const u16* W2,
            const float* b0, const float* b1, const float* b2,
            void* o0, void* o1, void* o2,
            int M, int L, int nrope, int posoff,
            const float* __restrict__ cosT, const float* __restrict__ sinT)
{
  __shared__ __align__(16) u16 As[128 * 32];
  __shared__ __align__(16) u16 Bs[128 * 32];
  int z = blockIdx.z;
  const u16* Wt = (z == 0) ? W0 : ((z == 1) ? W1 : W2);
  const float* bias = (z == 0) ? b0 : ((z == 1) ? b1 : b2);
  void* outp = (z == 0) ? o0 : ((z == 1) ? o1 : o2);

  int tid = threadIdx.x;
  int lane = tid & 63, w = tid >> 6;
  int wr = w >> 1, wc = w & 1;
  int rowBase = blockIdx.y * 128;
  int colBase = blockIdx.x * 128;

  f32x4 acc[4][4] = {};

  int lr = lane >> 2, l4 = lane & 3;
  const u16* srcA0 = A + (size_t)(rowBase + w * 16 + lr) * EMBED + l4 * 8;
  const u16* srcA1 = srcA0 + 64 * EMBED;
  const u16* srcB0 = Wt + (size_t)(colBase + w * 16 + lr) * EMBED + l4 * 8;
  const u16* srcB1 = srcB0 + 64 * EMBED;
  u16* dstA = As + w * 512;
  u16* dstB = Bs + w * 512;

  int aoff = (lane & 15) * 32 + (lane >> 4) * 8;
  const u16* fA = As + wr * 2048 + aoff;
  const u16* fB = Bs + wc * 2048 + aoff;

  for (int k0 = 0; k0 < EMBED; k0 += 32) {
    gload16(srcA0 + k0, dstA);
    gload16(srcA1 + k0, dstA + 2048);
    gload16(srcB0 + k0, dstB);
    gload16(srcB1 + k0, dstB + 2048);
    __syncthreads();
    short8 af[4], bfv[4];
#pragma unroll
    for (int mi = 0; mi < 4; ++mi) af[mi] = *(const short8*)(fA + mi * 512);
#pragma unroll
    for (int ni = 0; ni < 4; ++ni) bfv[ni] = *(const short8*)(fB + ni * 512);
#pragma unroll
    for (int mi = 0; mi < 4; ++mi)
#pragma unroll
      for (int ni = 0; ni < 4; ++ni)
        acc[mi][ni] = __builtin_amdgcn_mfma_f32_16x16x32_bf16(af[mi], bfv[ni], acc[mi][ni], 0, 0, 0);
    __syncthreads();
  }

  int c15 = lane & 15, rgrp = (lane >> 4) * 4;
  if (OUTMODE == 1) {
    float* out = (float*)outp;
#pragma unroll
    for (int mi = 0; mi < 4; ++mi)
#pragma unroll
      for (int r = 0; r < 4; ++r) {
        int m = rowBase + wr * 64 + mi * 16 + rgrp + r;
#pragma unroll
        for (int ni = 0; ni < 4; ++ni) {
          int n = colBase + wc * 64 + ni * 16 + c15;
          out[(size_t)m * EMBED + n] = acc[mi][ni][r] + bias[n];
        }
      }
  } else {
    u16* out = (u16*)outp;
    int h = (colBase >> 6) + wc;           // wave spans exactly one head
    bool dorope = (z < nrope);
#pragma unroll
    for (int mi = 0; mi < 4; ++mi)
#pragma unroll
      for (int r = 0; r < 4; ++r) {
        int m = rowBase + wr * 64 + mi * 16 + rgrp + r;
        int bidx = (m >= L) ? 1 : 0;
        int l = m - bidx * L;
        size_t obase = ((size_t)(bidx * HEADS + h) * L + l) * HDIM;
        if (dorope) {
          int pos = posoff + l;
#pragma unroll
          for (int ni = 0; ni < 2; ++ni) {
            int d = ni * 16 + c15;                  // d in [0,32)
            float c = cosT[pos * 32 + d], s = sinT[pos * 32 + d];
            float x0 = acc[mi][ni][r] + bias[h * 64 + d];
            float x2 = acc[mi][ni + 2][r] + bias[h * 64 + d + 32];
            out[obase + d]      = f2bf(x0 * c - x2 * s);
            out[obase + d + 32] = f2bf(x2 * c + x0 * s);
          }
        } else {
#pragma unroll
          for (int ni = 0; ni < 4; ++ni) {
            int d = ni * 16 + c15;
            out[obase + d] = f2bf(acc[mi][ni][r] + bias[h * 64 + d]);
          }
        }
      }
  }
}

// ---------- attention helpers ----------
__device__ __forceinline__ void loadq(const u16* qrow, float* qf) {
  const uint4* qp = (const uint4*)qrow;
#pragma unroll
  for (int c = 0; c < 8; ++c) {
    uint4 u = qp[c];
    up2(u.x, qf[c * 8 + 0], qf[c * 8 + 1]);
    up2(u.y, qf[c * 8 + 2], qf[c * 8 + 3]);
    up2(u.z, qf[c * 8 + 4], qf[c * 8 + 5]);
    up2(u.w, qf[c * 8 + 6], qf[c * 8 + 7]);
  }
}
__device__ __forceinline__ float dot64(const float* qf, const u16* krow) {
  const uint4* kp = (const uint4*)krow;
  float s = 0.f;
#pragma unroll
  for (int c = 0; c < 8; ++c) {
    uint4 u = kp[c];
    float a0, a1, a2, a3, a4, a5, a6, a7;
    up2(u.x, a0, a1); up2(u.y, a2, a3); up2(u.z, a4, a5); up2(u.w, a6, a7);
    s += qf[c * 8 + 0] * a0 + qf[c * 8 + 1] * a1 + qf[c * 8 + 2] * a2 + qf[c * 8 + 3] * a3
       + qf[c * 8 + 4] * a4 + qf[c * 8 + 5] * a5 + qf[c * 8 + 6] * a6 + qf[c * 8 + 7] * a7;
  }
  return s;
}

// ---------- stage-1 attention: summary queries, keys = [sum(0..i); reg bar i] ----------
__global__ __launch_bounds__(256)
void attn1_k(const u16* __restrict__ Qs, const u16* __restrict__ Ks,
             const u16* __restrict__ Vs, const u16* __restrict__ Kr,
             const u16* __restrict__ Vr, u16* __restrict__ outA)
{
  int bh = blockIdx.x; int b = bh >> 4, h = bh & 15;
  int lane = threadIdx.x & 63, w = threadIdx.x >> 6;
  const u16* qB = Qs + (size_t)bh * SLEN * HDIM;
  const u16* kS = Ks + (size_t)bh * SLEN * HDIM;
  const u16* vS = Vs + (size_t)bh * SLEN * HDIM;
  const u16* kR = Kr + (size_t)bh * RLEN * HDIM;
  const u16* vR = Vr + (size_t)bh * RLEN * HDIM;

  for (int qi = w * 16; qi < w * 16 + 16; ++qi) {
    float qf[64];
    loadq(qB + qi * HDIM, qf);
    bool v1 = (lane <= qi);
    bool v2 = (lane < 32);
    float s1 = v1 ? dot64(qf, kS + lane * HDIM) : 0.f;
    float s2 = v2 ? dot64(qf, kR + (qi * 32 + lane) * HDIM) : 0.f;
    float sc1 = v1 ? s1 * 0.125f : -1e30f;
    float sc2 = v2 ? s2 * 0.125f : -1e30f;
    float mx = fmaxf(sc1, sc2);
#pragma unroll
    for (int off = 32; off; off >>= 1) mx = fmaxf(mx, __shfl_xor(mx, off));
    float e1 = v1 ? __expf(sc1 - mx) : 0.f;
    float e2 = v2 ? __expf(sc2 - mx) : 0.f;
    float sm = e1 + e2;
#pragma unroll
    for (int off = 32; off; off >>= 1) sm += __shfl_xor(sm, off);
    float inv = 1.f / sm;
    float accv = 0.f;
    for (int j = 0; j <= qi; ++j) {
      float pj = __shfl(e1, j);
      accv += pj * bf2f(vS[j * HDIM + lane]);
    }
    const u16* vrow = vR + (size_t)qi * 32 * HDIM + lane;
#pragma unroll 8
    for (int j = 0; j < 32; ++j) {
      float pj = __shfl(e2, j);
      accv += pj * bf2f(vrow[j * HDIM]);
    }
    outA[((size_t)(b * SLEN + qi)) * EMBED + h * HDIM + lane] = f2bf(accv * inv);
  }
}

// ---------- stage-2 attention: regular queries, keys = [sum2(0..t/32); reg bar prefix] ----------
__global__ __launch_bounds__(256)
void attn2_k(const u16* __restrict__ Qr, const u16* __restrict__ Kr,
             const u16* __restrict__ Vr, const u16* __restrict__ Ks2,
             const u16* __restrict__ Vs2, u16* __restrict__ outA)
{
  int bh = blockIdx.y; int b = bh >> 4, h = bh & 15;
  int lane = threadIdx.x & 63, w = threadIdx.x >> 6;
  const u16* qB = Qr + (size_t)bh * RLEN * HDIM;
  const u16* kR = Kr + (size_t)bh * RLEN * HDIM;
  const u16* vR = Vr + (size_t)bh * RLEN * HDIM;
  const u16* kS = Ks2 + (size_t)bh * SLEN * HDIM;
  const u16* vS = Vs2 + (size_t)bh * SLEN * HDIM;
  int t0 = blockIdx.x * 32 + w * 8;
  for (int t = t0; t < t0 + 8; ++t) {
    int B0 = t >> 5;
    int nS = B0 + 1, nR = (t & 31) + 1;
    float qf[64];
    loadq(qB + t * HDIM, qf);
    bool v1 = (lane < nS);
    bool v2 = (lane < nR);
    float s1 = v1 ? dot64(qf, kS + lane * HDIM) : 0.f;
    float s2 = v2 ? dot64(qf, kR + (B0 * 32 + lane) * HDIM) : 0.f;
    float sc1 = v1 ? s1 * 0.125f : -1e30f;
    float sc2 = v2 ? s2 * 0.125f : -1e30f;
    float mx = fmaxf(sc1, sc2);
#pragma unroll
    for (int off = 32; off; off >>= 1) mx = fmaxf(mx, __shfl_xor(mx, off));
    float e1 = v1 ? __expf(sc1 - mx) : 0.f;
    float e2 = v2 ? __expf(sc2 - mx) : 0.f;
    float sm = e1 + e2;
#pragma unroll
    for (int off = 32; off; off >>= 1) sm += __shfl_xor(sm, off);
    float inv = 1.f / sm;
    float accv = 0.f;
    for (int j = 0; j < nS; ++j) {
      float pj = __shfl(e1, j);
      accv += pj * bf2f(vS[j * HDIM + lane]);
    }
    const u16* vrow = vR + (size_t)B0 * 32 * HDIM + lane;
    for (int j = 0; j < nR; ++j) {
      float pj = __shfl(e2, j);
      accv += pj * bf2f(vrow[j * HDIM]);
    }
    outA[((size_t)(b * RLEN + t)) * EMBED + h * HDIM + lane] = f2bf(accv * inv);
  }
}

// ---------- host ----------
extern "C" void kernel_launch(void* const* d_in, const int* in_sizes, int n_in,
                              void* d_out, int out_size, void* d_ws, size_t ws_size,
                              hipStream_t stream) {
  const float* sum_x = (const float*)d_in[0];
  const float* reg_x = (const float*)d_in[1];
  // d_in[2], d_in[3]: masks — structural, recomputed analytically, unused.
  const float* W[10]; const float* Bv[10];
  for (int i = 0; i < 10; ++i) {
    W[i] = (const float*)d_in[4 + 2 * i];
    Bv[i] = (const float*)d_in[5 + 2 * i];
  }
  // W order: 0 wq_s, 1 wk_s, 2 wv_s, 3 wo_s, 4 wq_r, 5 wk_r, 6 wv_r, 7 wo_r, 8 wk2, 9 wv2

  char* ws = (char*)d_ws;
  size_t off = 0;
  auto alloc = [&](size_t bytes) -> void* {
    void* p = ws + off;
    off += (bytes + 255) & ~(size_t)255;
    return p;
  };

  const size_t SX = (size_t)NBATCH * SLEN * EMBED;   // 131072
  const size_t RX = (size_t)NBATCH * RLEN * EMBED;   // 4194304

  float* cosT = (float*)alloc((size_t)TOTKV * 32 * 4);
  float* sinT = (float*)alloc((size_t)TOTKV * 32 * 4);
  u16* sxb = (u16*)alloc(SX * 2);
  u16* rxb = (u16*)alloc(RX * 2);
  u16* Wt  = (u16*)alloc((size_t)10 * EMBED * EMBED * 2);
  u16* Qs = (u16*)alloc(SX * 2);
  u16* Ks = (u16*)alloc(SX * 2);
  u16* Vs = (u16*)alloc(SX * 2);
  u16* Qr = (u16*)alloc(RX * 2);
  u16* Kr = (u16*)alloc(RX * 2);
  u16* Vr = (u16*)alloc(RX * 2);
  u16* sattn = (u16*)alloc(SX * 2);
  u16* Ks2 = (u16*)alloc(SX * 2);
  u16* Vs2 = (u16*)alloc(SX * 2);
  u16* rattn = (u16*)alloc(RX * 2);
  (void)ws_size; (void)in_sizes; (void)n_in; (void)out_size;

  rope_table_k<<<(TOTKV * 32 + 255) / 256, 256, 0, stream>>>(cosT, sinT);
  f2bf_k<<<(int)(SX / 4 + 255) / 256, 256, 0, stream>>>(sum_x, sxb, (int)SX);
  f2bf_k<<<(int)(RX / 4 + 255) / 256, 256, 0, stream>>>(reg_x, rxb, (int)RX);
  WSrc wsrc;
  for (int i = 0; i < 10; ++i) wsrc.p[i] = W[i];
  transpose_w_k<<<dim3(16, 16, 10), 256, 0, stream>>>(wsrc, Wt);

#define WT(i) (Wt + (size_t)(i) * EMBED * EMBED)
  // sum QKV (+RoPE on q,k), pos offset 0
  gemm_k<0><<<dim3(8, 1, 3), 256, 0, stream>>>(sxb, WT(0), WT(1), WT(2),
      Bv[0], Bv[1], Bv[2], Qs, Ks, Vs, 128, 64, 2, 0, cosT, sinT);
  // reg QKV (+RoPE on q,k), pos offset 64
  gemm_k<0><<<dim3(8, 32, 3), 256, 0, stream>>>(rxb, WT(4), WT(5), WT(6),
      Bv[4], Bv[5], Bv[6], Qr, Kr, Vr, 4096, 2048, 2, 64, cosT, sinT);
  // stage-1 attention -> sattn (B,S,E) bf16
  attn1_k<<<32, 256, 0, stream>>>(Qs, Ks, Vs, Kr, Vr, sattn);
  // k2/v2 projections of sattn (no rope)
  gemm_k<0><<<dim3(8, 1, 2), 256, 0, stream>>>(sattn, WT(8), WT(9), WT(8),
      Bv[8], Bv[9], Bv[8], Ks2, Vs2, Ks2, 128, 64, 0, 0, cosT, sinT);
  // stage-2 attention -> rattn (B,R,E) bf16
  attn2_k<<<dim3(64, 32), 256, 0, stream>>>(Qr, Kr, Vr, Ks2, Vs2, rattn);
  // output projections -> d_out (f32)
  float* outS = (float*)d_out;
  float* outR = outS + SX;
  gemm_k<1><<<dim3(8, 1, 1), 256, 0, stream>>>(sattn, WT(3), WT(3), WT(3),
      Bv[3], Bv[3], Bv[3], outS, outS, outS, 128, 64, 0, 0, cosT, sinT);
  gemm_k<1><<<dim3(8, 32, 1), 256, 0, stream>>>(rattn, WT(7), WT(7), WT(7),
      Bv[7], Bv[7], Bv[7], outR, outR, outR, 4096, 2048, 0, 0, cosT, sinT);
#undef WT
}

// Round 2
// 196.280 us; speedup vs baseline: 3.1516x; 3.1516x over previous
//
#include <hip/hip_runtime.h>
#include <stdint.h>

typedef unsigned short u16;
typedef unsigned int u32;
typedef __attribute__((ext_vector_type(8))) short short8;
typedef __attribute__((ext_vector_type(4))) float f32x4;

#define EMBED 1024
#define HEADS 16
#define HDIM 64
#define NBATCH 2
#define SLEN 64
#define RLEN 2048
#define TOTKV (SLEN + RLEN)   // 2112

// ---------- small helpers ----------
__device__ __forceinline__ float bf2f(u16 u) {
  union { u32 i; float f; } v; v.i = ((u32)u) << 16; return v.f;
}
__device__ __forceinline__ u16 f2bf(float f) {
  union { float f; u32 i; } v; v.f = f;
  return (u16)((v.i + 0x7fffu + ((v.i >> 16) & 1u)) >> 16);  // RNE
}
__device__ __forceinline__ void up2(u32 u, float& a, float& b) {
  union { u32 i; float f; } x, y;
  x.i = u << 16; y.i = u & 0xffff0000u;
  a = x.f; b = y.f;
}
__device__ __forceinline__ void gload16(const void* g, void* l) {
  __builtin_amdgcn_global_load_lds((const __attribute__((address_space(1))) u32*)g,
                                   (__attribute__((address_space(3))) u32*)l, 16, 0, 0);
}

// ---------- RoPE table ----------
__global__ void rope_table_k(float* __restrict__ cosT, float* __restrict__ sinT) {
  int idx = blockIdx.x * blockDim.x + threadIdx.x;
  if (idx >= TOTKV * 32) return;
  int pos = idx >> 5, i = idx & 31;
  float inv = powf(10000.0f, -(float)i / 32.0f);
  float a = (float)pos * inv;
  float s, c;
  sincosf(a, &s, &c);
  cosT[idx] = c; sinT[idx] = s;
}

// ---------- f32 -> bf16 convert ----------
__global__ void f2bf_k(const float* __restrict__ src, u16* __restrict__ dst, int n) {
  int i = (blockIdx.x * blockDim.x + threadIdx.x) * 4;
  if (i >= n) return;
  float4 v = *(const float4*)(src + i);
  u32 lo = (u32)f2bf(v.x) | ((u32)f2bf(v.y) << 16);
  u32 hi = (u32)f2bf(v.z) | ((u32)f2bf(v.w) << 16);
  uint2 o; o.x = lo; o.y = hi;
  *(uint2*)(dst + i) = o;
}

// ---------- weight transpose: W[k][n] f32 -> Wt[n][k] bf16 ----------
struct WSrc { const float* p[10]; };
__global__ void transpose_w_k(WSrc wsrc, u16* __restrict__ dst) {
  __shared__ float tile[64][65];
  const float* src = wsrc.p[blockIdx.z];
  u16* out = dst + (size_t)blockIdx.z * (EMBED * (size_t)EMBED);
  int t = threadIdx.x;
  int k0 = blockIdx.y * 64, n0 = blockIdx.x * 64;
  int r0 = t >> 4, c0 = (t & 15) * 4;
#pragma unroll
  for (int i = 0; i < 4; ++i) {
    int r = i * 16 + r0;
    float4 v = *(const float4*)(src + (size_t)(k0 + r) * EMBED + n0 + c0);
    tile[r][c0] = v.x; tile[r][c0 + 1] = v.y; tile[r][c0 + 2] = v.z; tile[r][c0 + 3] = v.w;
  }
  __syncthreads();
#pragma unroll
  for (int i = 0; i < 4; ++i) {
    int n = i * 16 + r0;
    uint2 o;
    o.x = (u32)f2bf(tile[c0][n]) | ((u32)f2bf(tile[c0 + 1][n]) << 16);
    o.y = (u32)f2bf(tile[c0 + 2][n]) | ((u32)f2bf(tile[c0 + 3][n]) << 16);
    *(uint2*)(out + (size_t)(n0 + n) * EMBED + k0 + c0) = o;
  }
}

// ---------- bf16 GEMM (m97-style) ----------
template<int OUTMODE>
__global__ __launch_bounds__(256)
void gemm_k(const u16* __restrict__ A,
            const u16* W0, const u16* W1, const u16* W2,
            const float* b0, const float* b1, const float* b2,
            void* o0, void* o1, void* o2,
            int M, int L, int nrope, int posoff,
            const float* __restrict__ cosT, const float* __restrict__ sinT)
{
  __shared__ __align__(16) u16 As[128 * 32];
  __shared__ __align__(16) u16 Bs[128 * 32];
  int z = blockIdx.z;
  const u16* Wt = (z == 0) ? W0 : ((z == 1) ? W1 : W2);
  const float* bias = (z == 0) ? b0 : ((z == 1) ? b1 : b2);
  void* outp = (z == 0) ? o0 : ((z == 1) ? o1 : o2);

  int tid = threadIdx.x;
  int lane = tid & 63, w = tid >> 6;
  int wr = w >> 1, wc = w & 1;
  int rowBase = blockIdx.y * 128;
  int colBase = blockIdx.x * 128;

  f32x4 acc[4][4] = {};

  int lr = lane >> 2, l4 = lane & 3;
  const u16* srcA0 = A + (size_t)(rowBase + w * 16 + lr) * EMBED + l4 * 8;
  const u16* srcA1 = srcA0 + 64 * EMBED;
  const u16* srcB0 = Wt + (size_t)(colBase + w * 16 + lr) * EMBED + l4 * 8;
  const u16* srcB1 = srcB0 + 64 * EMBED;
  u16* dstA = As + w * 512;
  u16* dstB = Bs + w * 512;

  int aoff = (lane & 15) * 32 + (lane >> 4) * 8;
  const u16* fA = As + wr * 2048 + aoff;
  const u16* fB = Bs + wc * 2048 + aoff;

  for (int k0 = 0; k0 < EMBED; k0 += 32) {
    gload16(srcA0 + k0, dstA);
    gload16(srcA1 + k0, dstA + 2048);
    gload16(srcB0 + k0, dstB);
    gload16(srcB1 + k0, dstB + 2048);
    __syncthreads();
    short8 af[4], bfv[4];
#pragma unroll
    for (int mi = 0; mi < 4; ++mi) af[mi] = *(const short8*)(fA + mi * 512);
#pragma unroll
    for (int ni = 0; ni < 4; ++ni) bfv[ni] = *(const short8*)(fB + ni * 512);
#pragma unroll
    for (int mi = 0; mi < 4; ++mi)
#pragma unroll
      for (int ni = 0; ni < 4; ++ni)
        acc[mi][ni] = __builtin_amdgcn_mfma_f32_16x16x32_bf16(af[mi], bfv[ni], acc[mi][ni], 0, 0, 0);
    __syncthreads();
  }

  int c15 = lane & 15, rgrp = (lane >> 4) * 4;
  if (OUTMODE == 1) {
    float* out = (float*)outp;
#pragma unroll
    for (int mi = 0; mi < 4; ++mi)
#pragma unroll
      for (int r = 0; r < 4; ++r) {
        int m = rowBase + wr * 64 + mi * 16 + rgrp + r;
#pragma unroll
        for (int ni = 0; ni < 4; ++ni) {
          int n = colBase + wc * 64 + ni * 16 + c15;
          out[(size_t)m * EMBED + n] = acc[mi][ni][r] + bias[n];
        }
      }
  } else {
    u16* out = (u16*)outp;
    int h = (colBase >> 6) + wc;
    bool dorope = (z < nrope);
#pragma unroll
    for (int mi = 0; mi < 4; ++mi)
#pragma unroll
      for (int r = 0; r < 4; ++r) {
        int m = rowBase + wr * 64 + mi * 16 + rgrp + r;
        int bidx = (m >= L) ? 1 : 0;
        int l = m - bidx * L;
        size_t obase = ((size_t)(bidx * HEADS + h) * L + l) * HDIM;
        if (dorope) {
          int pos = posoff + l;
#pragma unroll
          for (int ni = 0; ni < 2; ++ni) {
            int d = ni * 16 + c15;
            float c = cosT[pos * 32 + d], s = sinT[pos * 32 + d];
            float x0 = acc[mi][ni][r] + bias[h * 64 + d];
            float x2 = acc[mi][ni + 2][r] + bias[h * 64 + d + 32];
            out[obase + d]      = f2bf(x0 * c - x2 * s);
            out[obase + d + 32] = f2bf(x2 * c + x0 * s);
          }
        } else {
#pragma unroll
          for (int ni = 0; ni < 4; ++ni) {
            int d = ni * 16 + c15;
            out[obase + d] = f2bf(acc[mi][ni][r] + bias[h * 64 + d]);
          }
        }
      }
  }
}

// ---------- attention helpers ----------
__device__ __forceinline__ void loadq(const u16* qrow, float* qf) {
  const uint4* qp = (const uint4*)qrow;
#pragma unroll
  for (int c = 0; c < 8; ++c) {
    uint4 u = qp[c];
    up2(u.x, qf[c * 8 + 0], qf[c * 8 + 1]);
    up2(u.y, qf[c * 8 + 2], qf[c * 8 + 3]);
    up2(u.z, qf[c * 8 + 4], qf[c * 8 + 5]);
    up2(u.w, qf[c * 8 + 6], qf[c * 8 + 7]);
  }
}
__device__ __forceinline__ float dot64(const float* qf, const u16* krow) {
  const uint4* kp = (const uint4*)krow;
  float s = 0.f;
#pragma unroll
  for (int c = 0; c < 8; ++c) {
    uint4 u = kp[c];
    float a0, a1, a2, a3, a4, a5, a6, a7;
    up2(u.x, a0, a1); up2(u.y, a2, a3); up2(u.z, a4, a5); up2(u.w, a6, a7);
    s += qf[c * 8 + 0] * a0 + qf[c * 8 + 1] * a1 + qf[c * 8 + 2] * a2 + qf[c * 8 + 3] * a3
       + qf[c * 8 + 4] * a4 + qf[c * 8 + 5] * a5 + qf[c * 8 + 6] * a6 + qf[c * 8 + 7] * a7;
  }
  return s;
}

// ---------- stage-1 attention: one query per wave, fixed-bound unrolled PV ----------
__global__ __launch_bounds__(256)
void attn1_k(const u16* __restrict__ Qs, const u16* __restrict__ Ks,
             const u16* __restrict__ Vs, const u16* __restrict__ Kr,
             const u16* __restrict__ Vr, u16* __restrict__ outA)
{
  int gw = blockIdx.x * 4 + (threadIdx.x >> 6);  // 2048 waves total
  int bh = gw >> 6, qi = gw & 63;
  int b = bh >> 4, h = bh & 15;
  int lane = threadIdx.x & 63;
  const u16* qB = Qs + (size_t)bh * SLEN * HDIM;
  const u16* kS = Ks + (size_t)bh * SLEN * HDIM;
  const u16* vS = Vs + (size_t)bh * SLEN * HDIM;
  const u16* kR = Kr + (size_t)bh * RLEN * HDIM;
  const u16* vR = Vr + (size_t)bh * RLEN * HDIM;

  float qf[64];
  loadq(qB + qi * HDIM, qf);
  bool v1 = (lane <= qi);
  bool v2 = (lane < 32);
  float s1 = v1 ? dot64(qf, kS + lane * HDIM) : 0.f;
  float s2 = v2 ? dot64(qf, kR + (qi * 32 + lane) * HDIM) : 0.f;
  float sc1 = v1 ? s1 * 0.125f : -1e30f;
  float sc2 = v2 ? s2 * 0.125f : -1e30f;
  float mx = fmaxf(sc1, sc2);
#pragma unroll
  for (int off = 32; off; off >>= 1) mx = fmaxf(mx, __shfl_xor(mx, off));
  float e1 = v1 ? __expf(sc1 - mx) : 0.f;
  float e2 = v2 ? __expf(sc2 - mx) : 0.f;
  float sm = e1 + e2;
#pragma unroll
  for (int off = 32; off; off >>= 1) sm += __shfl_xor(sm, off);
  float inv = 1.f / sm;

  float a0 = 0.f, a1 = 0.f, a2 = 0.f, a3 = 0.f;
  const u16* vrow = vR + (size_t)qi * 32 * HDIM + lane;
#pragma unroll
  for (int j = 0; j < 64; j += 4) {
    a0 += __shfl(e1, j + 0) * bf2f(vS[(j + 0) * HDIM + lane]);
    a1 += __shfl(e1, j + 1) * bf2f(vS[(j + 1) * HDIM + lane]);
    a2 += __shfl(e1, j + 2) * bf2f(vS[(j + 2) * HDIM + lane]);
    a3 += __shfl(e1, j + 3) * bf2f(vS[(j + 3) * HDIM + lane]);
  }
#pragma unroll
  for (int j = 0; j < 32; j += 4) {
    a0 += __shfl(e2, j + 0) * bf2f(vrow[(j + 0) * HDIM]);
    a1 += __shfl(e2, j + 1) * bf2f(vrow[(j + 1) * HDIM]);
    a2 += __shfl(e2, j + 2) * bf2f(vrow[(j + 2) * HDIM]);
    a3 += __shfl(e2, j + 3) * bf2f(vrow[(j + 3) * HDIM]);
  }
  float accv = (a0 + a1) + (a2 + a3);
  outA[((size_t)(b * SLEN + qi)) * EMBED + h * HDIM + lane] = f2bf(accv * inv);
}

// ---------- stage-2 attention: MFMA per (b,h,bar) block ----------
// Keys: cols 0..63 = summary K2 (valid col <= bar), cols 64..95 = bar's reg K (causal).
__global__ __launch_bounds__(256)
void attn2_k(const u16* __restrict__ Qr, const u16* __restrict__ Kr,
             const u16* __restrict__ Vr, const u16* __restrict__ Ks2,
             const u16* __restrict__ Vs2, u16* __restrict__ outA)
{
  __shared__ __align__(16) float Sf[32][104];   // scores
  __shared__ __align__(16) u16 Pb[32][104];     // probs bf16
  __shared__ __align__(16) u16 Vt[64][104];     // V^T: [d][key]

  int bar = blockIdx.x, bh = blockIdx.y;
  int b = bh >> 4, h = bh & 15;
  int nS = bar + 1;
  int tid = threadIdx.x, lane = tid & 63, w = tid >> 6;
  int l15 = lane & 15, lg = lane >> 4;

  const u16* qB = Qr + ((size_t)bh * RLEN + bar * 32) * HDIM;
  const u16* kS = Ks2 + (size_t)bh * SLEN * HDIM;
  const u16* kR = Kr + ((size_t)bh * RLEN + bar * 32) * HDIM;
  const u16* vS = Vs2 + (size_t)bh * SLEN * HDIM;
  const u16* vR = Vr + ((size_t)bh * RLEN + bar * 32) * HDIM;

  // stage V^T into LDS (keys 0..63 summary, 64..95 reg)
  for (int e = tid; e < 96 * 64; e += 256) {
    int key = e >> 6, d = e & 63;
    Vt[d][key] = (key < 64) ? vS[key * 64 + d] : vR[(key - 64) * 64 + d];
  }

  // QK^T: 12 tiles (2 qrow x 6 kcol), wave w -> tiles w*3..w*3+2
#pragma unroll
  for (int i = 0; i < 3; ++i) {
    int t = w * 3 + i, r = t / 6, c = t % 6;
    const u16* arow = qB + (r * 16 + l15) * 64 + lg * 8;
    const u16* brow = (c < 4) ? (kS + (c * 16 + l15) * 64 + lg * 8)
                              : (kR + ((c - 4) * 16 + l15) * 64 + lg * 8);
    f32x4 acc = {};
    acc = __builtin_amdgcn_mfma_f32_16x16x32_bf16(*(const short8*)arow,
                                                  *(const short8*)brow, acc, 0, 0, 0);
    acc = __builtin_amdgcn_mfma_f32_16x16x32_bf16(*(const short8*)(arow + 32),
                                                  *(const short8*)(brow + 32), acc, 0, 0, 0);
#pragma unroll
    for (int j = 0; j < 4; ++j)
      Sf[r * 16 + lg * 4 + j][c * 16 + l15] = acc[j] * 0.125f;
  }
  __syncthreads();

  // softmax: wave w handles rows w*8..w*8+7; 8 lanes per row
  {
    int r = w * 8 + (lane >> 3), sub = lane & 7;
    float vals[12];
    float mx = -1e30f;
#pragma unroll
    for (int j = 0; j < 12; ++j) {
      int c = sub + 8 * j;
      bool valid = (c < nS) || (c >= 64 && c < 96 && (c - 64) <= r);
      float v = valid ? Sf[r][c] : -1e30f;
      vals[j] = v;
      mx = fmaxf(mx, v);
    }
#pragma unroll
    for (int off = 1; off < 8; off <<= 1) mx = fmaxf(mx, __shfl_xor(mx, off));
    float sm = 0.f;
#pragma unroll
    for (int j = 0; j < 12; ++j) {
      vals[j] = __expf(vals[j] - mx);
      sm += vals[j];
    }
#pragma unroll
    for (int off = 1; off < 8; off <<= 1) sm += __shfl_xor(sm, off);
    float inv = 1.f / sm;
#pragma unroll
    for (int j = 0; j < 12; ++j) {
      int c = sub + 8 * j;
      Pb[r][c] = f2bf(vals[j] * inv);
    }
  }
  __syncthreads();

  // PV: O[32][64] = P[32][96] @ V[96][64]; 8 tiles (2 qrow x 4 dcol), wave w -> 2 tiles
#pragma unroll
  for (int i = 0; i < 2; ++i) {
    int t = w * 2 + i, r = t >> 2, dc = t & 3;
    f32x4 acc = {};
#pragma unroll
    for (int ks = 0; ks < 3; ++ks) {
      short8 a = *(const short8*)&Pb[r * 16 + l15][ks * 32 + lg * 8];
      short8 bb = *(const short8*)&Vt[dc * 16 + l15][ks * 32 + lg * 8];
      acc = __builtin_amdgcn_mfma_f32_16x16x32_bf16(a, bb, acc, 0, 0, 0);
    }
    int d = dc * 16 + l15;
#pragma unroll
    for (int j = 0; j < 4; ++j) {
      int qq = r * 16 + lg * 4 + j;
      int tt = bar * 32 + qq;
      outA[((size_t)(b * RLEN + tt)) * EMBED + h * 64 + d] = f2bf(acc[j]);
    }
  }
}

// ---------- host ----------
extern "C" void kernel_launch(void* const* d_in, const int* in_sizes, int n_in,
                              void* d_out, int out_size, void* d_ws, size_t ws_size,
                              hipStream_t stream) {
  const float* sum_x = (const float*)d_in[0];
  const float* reg_x = (const float*)d_in[1];
  const float* W[10]; const float* Bv[10];
  for (int i = 0; i < 10; ++i) {
    W[i] = (const float*)d_in[4 + 2 * i];
    Bv[i] = (const float*)d_in[5 + 2 * i];
  }

  char* ws = (char*)d_ws;
  size_t off = 0;
  auto alloc = [&](size_t bytes) -> void* {
    void* p = ws + off;
    off += (bytes + 255) & ~(size_t)255;
    return p;
  };

  const size_t SX = (size_t)NBATCH * SLEN * EMBED;
  const size_t RX = (size_t)NBATCH * RLEN * EMBED;

  float* cosT = (float*)alloc((size_t)TOTKV * 32 * 4);
  float* sinT = (float*)alloc((size_t)TOTKV * 32 * 4);
  u16* sxb = (u16*)alloc(SX * 2);
  u16* rxb = (u16*)alloc(RX * 2);
  u16* Wt  = (u16*)alloc((size_t)10 * EMBED * EMBED * 2);
  u16* Qs = (u16*)alloc(SX * 2);
  u16* Ks = (u16*)alloc(SX * 2);
  u16* Vs = (u16*)alloc(SX * 2);
  u16* Qr = (u16*)alloc(RX * 2);
  u16* Kr = (u16*)alloc(RX * 2);
  u16* Vr = (u16*)alloc(RX * 2);
  u16* sattn = (u16*)alloc(SX * 2);
  u16* Ks2 = (u16*)alloc(SX * 2);
  u16* Vs2 = (u16*)alloc(SX * 2);
  u16* rattn = (u16*)alloc(RX * 2);
  (void)ws_size; (void)in_sizes; (void)n_in; (void)out_size;

  rope_table_k<<<(TOTKV * 32 + 255) / 256, 256, 0, stream>>>(cosT, sinT);
  f2bf_k<<<(int)(SX / 4 + 255) / 256, 256, 0, stream>>>(sum_x, sxb, (int)SX);
  f2bf_k<<<(int)(RX / 4 + 255) / 256, 256, 0, stream>>>(reg_x, rxb, (int)RX);
  WSrc wsrc;
  for (int i = 0; i < 10; ++i) wsrc.p[i] = W[i];
  transpose_w_k<<<dim3(16, 16, 10), 256, 0, stream>>>(wsrc, Wt);

#define WT(i) (Wt + (size_t)(i) * EMBED * EMBED)
  gemm_k<0><<<dim3(8, 1, 3), 256, 0, stream>>>(sxb, WT(0), WT(1), WT(2),
      Bv[0], Bv[1], Bv[2], Qs, Ks, Vs, 128, 64, 2, 0, cosT, sinT);
  gemm_k<0><<<dim3(8, 32, 3), 256, 0, stream>>>(rxb, WT(4), WT(5), WT(6),
      Bv[4], Bv[5], Bv[6], Qr, Kr, Vr, 4096, 2048, 2, 64, cosT, sinT);
  attn1_k<<<512, 256, 0, stream>>>(Qs, Ks, Vs, Kr, Vr, sattn);
  gemm_k<0><<<dim3(8, 1, 2), 256, 0, stream>>>(sattn, WT(8), WT(9), WT(8),
      Bv[8], Bv[9], Bv[8], Ks2, Vs2, Ks2, 128, 64, 0, 0, cosT, sinT);
  attn2_k<<<dim3(64, 32), 256, 0, stream>>>(Qr, Kr, Vr, Ks2, Vs2, rattn);
  float* outS = (float*)d_out;
  float* outR = outS + SX;
  gemm_k<1><<<dim3(8, 1, 1), 256, 0, stream>>>(sattn, WT(3), WT(3), WT(3),
      Bv[3], Bv[3], Bv[3], outS, outS, outS, 128, 64, 0, 0, cosT, sinT);
  gemm_k<1><<<dim3(8, 32, 1), 256, 0, stream>>>(rattn, WT(7), WT(7), WT(7),
      Bv[7], Bv[7], Bv[7], outR, outR, outR, 4096, 2048, 0, 0, cosT, sinT);
#undef WT
}

// Round 3
// 178.013 us; speedup vs baseline: 3.4750x; 1.1026x over previous
//
#include <hip/hip_runtime.h>
#include <stdint.h>

typedef unsigned short u16;
typedef unsigned int u32;
typedef __attribute__((ext_vector_type(8))) short short8;
typedef __attribute__((ext_vector_type(4))) float f32x4;

#define EMBED 1024
#define HEADS 16
#define HDIM 64
#define NBATCH 2
#define SLEN 64
#define RLEN 2048
#define TOTKV (SLEN + RLEN)   // 2112

struct B10 { const float* p[10]; };

// ---------- small helpers ----------
__device__ __forceinline__ float bf2f(u16 u) {
  union { u32 i; float f; } v; v.i = ((u32)u) << 16; return v.f;
}
__device__ __forceinline__ u16 f2bf(float f) {
  union { float f; u32 i; } v; v.f = f;
  return (u16)((v.i + 0x7fffu + ((v.i >> 16) & 1u)) >> 16);  // RNE
}
__device__ __forceinline__ void up2(u32 u, float& a, float& b) {
  union { u32 i; float f; } x, y;
  x.i = u << 16; y.i = u & 0xffff0000u;
  a = x.f; b = y.f;
}
__device__ __forceinline__ void gload16(const void* g, void* l) {
  __builtin_amdgcn_global_load_lds((const __attribute__((address_space(1))) u32*)g,
                                   (__attribute__((address_space(3))) u32*)l, 16, 0, 0);
}

// XCD-aware bijective swizzle of linear block id (total % 8 == 0 assumed).
__device__ __forceinline__ void swz_block(int& bx, int& by, int& bz) {
  int gx = gridDim.x, gy = gridDim.y, gz = gridDim.z;
  int total = gx * gy * gz;
  int l = blockIdx.x + gx * (blockIdx.y + gy * blockIdx.z);
  if (total & 7) { bx = blockIdx.x; by = blockIdx.y; bz = blockIdx.z; return; }
  int nl = (l & 7) * (total >> 3) + (l >> 3);
  bx = nl % gx; int t = nl / gx; by = t % gy; bz = t / gy;
}

// ---------- RoPE table ----------
__global__ void rope_table_k(float* __restrict__ cosT, float* __restrict__ sinT) {
  int idx = blockIdx.x * blockDim.x + threadIdx.x;
  if (idx >= TOTKV * 32) return;
  int pos = idx >> 5, i = idx & 31;
  float inv = powf(10000.0f, -(float)i / 32.0f);
  float a = (float)pos * inv;
  float s, c;
  sincosf(a, &s, &c);
  cosT[idx] = c; sinT[idx] = s;
}

// ---------- f32 -> bf16 convert ----------
__global__ void f2bf_k(const float* __restrict__ src, u16* __restrict__ dst, int n) {
  int i = (blockIdx.x * blockDim.x + threadIdx.x) * 4;
  if (i >= n) return;
  float4 v = *(const float4*)(src + i);
  u32 lo = (u32)f2bf(v.x) | ((u32)f2bf(v.y) << 16);
  u32 hi = (u32)f2bf(v.z) | ((u32)f2bf(v.w) << 16);
  uint2 o; o.x = lo; o.y = hi;
  *(uint2*)(dst + i) = o;
}

// ---------- weight transpose: W[k][n] f32 -> Wt[n][k] bf16 ----------
struct WSrc { const float* p[10]; };
__global__ void transpose_w_k(WSrc wsrc, u16* __restrict__ dst) {
  __shared__ float tile[64][65];
  const float* src = wsrc.p[blockIdx.z];
  u16* out = dst + (size_t)blockIdx.z * (EMBED * (size_t)EMBED);
  int t = threadIdx.x;
  int k0 = blockIdx.y * 64, n0 = blockIdx.x * 64;
  int r0 = t >> 4, c0 = (t & 15) * 4;
#pragma unroll
  for (int i = 0; i < 4; ++i) {
    int r = i * 16 + r0;
    float4 v = *(const float4*)(src + (size_t)(k0 + r) * EMBED + n0 + c0);
    tile[r][c0] = v.x; tile[r][c0 + 1] = v.y; tile[r][c0 + 2] = v.z; tile[r][c0 + 3] = v.w;
  }
  __syncthreads();
#pragma unroll
  for (int i = 0; i < 4; ++i) {
    int n = i * 16 + r0;
    uint2 o;
    o.x = (u32)f2bf(tile[c0][n]) | ((u32)f2bf(tile[c0 + 1][n]) << 16);
    o.y = (u32)f2bf(tile[c0 + 2][n]) | ((u32)f2bf(tile[c0 + 3][n]) << 16);
    *(uint2*)(out + (size_t)(n0 + n) * EMBED + k0 + c0) = o;
  }
}

// ---------- shared GEMM core: 128x128 tile, BK=32, double-buffered LDS ----------
// As/Bs: u16[2*4096] each (two 128x32 buffers).
__device__ __forceinline__ void gemm_core(const u16* __restrict__ A, const u16* __restrict__ Wt,
                                          int rowBase, int colBase, int lane, int w,
                                          u16* As, u16* Bs, f32x4 (&acc)[4][4]) {
  int wr = w >> 1, wc = w & 1;
  int lr = lane >> 2, l4 = lane & 3;
  const u16* srcA0 = A + (size_t)(rowBase + w * 16 + lr) * EMBED + l4 * 8;
  const u16* srcA1 = srcA0 + 64 * EMBED;
  const u16* srcB0 = Wt + (size_t)(colBase + w * 16 + lr) * EMBED + l4 * 8;
  const u16* srcB1 = srcB0 + 64 * EMBED;
  u16* dstA = As + w * 512;
  u16* dstB = Bs + w * 512;
  int aoff = (lane & 15) * 32 + (lane >> 4) * 8;
  const u16* fA = As + wr * 2048 + aoff;
  const u16* fB = Bs + wc * 2048 + aoff;

  // prologue: stage K-tile 0 into buffer 0
  gload16(srcA0, dstA);
  gload16(srcA1, dstA + 2048);
  gload16(srcB0, dstB);
  gload16(srcB1, dstB + 2048);
  __syncthreads();

  int cur = 0;
#pragma unroll 2
  for (int k0 = 0; k0 < EMBED; k0 += 32) {
    int nxt = cur ^ 1;
    if (k0 + 32 < EMBED) {           // issue next-tile staging BEFORE compute
      gload16(srcA0 + k0 + 32, dstA + nxt * 4096);
      gload16(srcA1 + k0 + 32, dstA + nxt * 4096 + 2048);
      gload16(srcB0 + k0 + 32, dstB + nxt * 4096);
      gload16(srcB1 + k0 + 32, dstB + nxt * 4096 + 2048);
    }
    const u16* fAc = fA + cur * 4096;
    const u16* fBc = fB + cur * 4096;
    short8 af[4], bfv[4];
#pragma unroll
    for (int mi = 0; mi < 4; ++mi) af[mi] = *(const short8*)(fAc + mi * 512);
#pragma unroll
    for (int ni = 0; ni < 4; ++ni) bfv[ni] = *(const short8*)(fBc + ni * 512);
#pragma unroll
    for (int mi = 0; mi < 4; ++mi)
#pragma unroll
      for (int ni = 0; ni < 4; ++ni)
        acc[mi][ni] = __builtin_amdgcn_mfma_f32_16x16x32_bf16(af[mi], bfv[ni], acc[mi][ni], 0, 0, 0);
    __syncthreads();                 // drains staging of nxt + everyone done reading cur
    cur = nxt;
  }
}

// mode 0: bf16 headsplit + rope; mode 1: bf16 headsplit; mode 2: f32 row-major
__device__ __forceinline__ void gemm_epilogue(f32x4 (&acc)[4][4], int mode, void* outp,
                                              const float* bias, int rowBase, int colBase,
                                              int L, int posoff, int lane, int w,
                                              const float* cosT, const float* sinT) {
  int wr = w >> 1, wc = w & 1;
  int c15 = lane & 15, rgrp = (lane >> 4) * 4;
  if (mode == 2) {
    float* out = (float*)outp;
#pragma unroll
    for (int mi = 0; mi < 4; ++mi)
#pragma unroll
      for (int r = 0; r < 4; ++r) {
        int m = rowBase + wr * 64 + mi * 16 + rgrp + r;
#pragma unroll
        for (int ni = 0; ni < 4; ++ni) {
          int n = colBase + wc * 64 + ni * 16 + c15;
          out[(size_t)m * EMBED + n] = acc[mi][ni][r] + bias[n];
        }
      }
  } else {
    u16* out = (u16*)outp;
    int h = (colBase >> 6) + wc;
    bool dorope = (mode == 0);
#pragma unroll
    for (int mi = 0; mi < 4; ++mi)
#pragma unroll
      for (int r = 0; r < 4; ++r) {
        int m = rowBase + wr * 64 + mi * 16 + rgrp + r;
        int bidx = (m >= L) ? 1 : 0;
        int l = m - bidx * L;
        size_t obase = ((size_t)(bidx * HEADS + h) * L + l) * HDIM;
        if (dorope) {
          int pos = posoff + l;
#pragma unroll
          for (int ni = 0; ni < 2; ++ni) {
            int d = ni * 16 + c15;
            float c = cosT[pos * 32 + d], s = sinT[pos * 32 + d];
            float x0 = acc[mi][ni][r] + bias[h * 64 + d];
            float x2 = acc[mi][ni + 2][r] + bias[h * 64 + d + 32];
            out[obase + d]      = f2bf(x0 * c - x2 * s);
            out[obase + d + 32] = f2bf(x2 * c + x0 * s);
          }
        } else {
#pragma unroll
          for (int ni = 0; ni < 4; ++ni) {
            int d = ni * 16 + c15;
            out[obase + d] = f2bf(acc[mi][ni][r] + bias[h * 64 + d]);
          }
        }
      }
  }
}

// ---------- fused QKV GEMM: grid (8, 33, 3); by==32 -> summary side ----------
__global__ __launch_bounds__(256)
void qkv_gemm_k(const u16* __restrict__ rxb, const u16* __restrict__ sxb,
                const u16* __restrict__ Wt_all, B10 biases,
                u16* Qs, u16* Ks, u16* Vs, u16* Qr, u16* Kr, u16* Vr,
                const float* __restrict__ cosT, const float* __restrict__ sinT)
{
  __shared__ __align__(16) u16 As[2 * 4096];
  __shared__ __align__(16) u16 Bs[2 * 4096];
  int bx, by, bz;
  swz_block(bx, by, bz);

  bool issum = (by == 32);
  const u16* A = issum ? sxb : rxb;
  int rowBase = issum ? 0 : by * 128;
  int L = issum ? SLEN : RLEN;
  int posoff = issum ? 0 : SLEN;
  int widx = issum ? bz : 4 + bz;
  const u16* Wt = Wt_all + (size_t)widx * EMBED * EMBED;
  const float* bias = biases.p[widx];
  u16* out = issum ? (bz == 0 ? Qs : (bz == 1 ? Ks : Vs))
                   : (bz == 0 ? Qr : (bz == 1 ? Kr : Vr));
  int mode = (bz < 2) ? 0 : 1;
  int colBase = bx * 128;
  int lane = threadIdx.x & 63, w = threadIdx.x >> 6;

  f32x4 acc[4][4] = {};
  gemm_core(A, Wt, rowBase, colBase, lane, w, As, Bs, acc);
  gemm_epilogue(acc, mode, out, bias, rowBase, colBase, L, posoff, lane, w, cosT, sinT);
}

// ---------- generic GEMM: z selects (W, bias, out, mode) ----------
__global__ __launch_bounds__(256)
void gemm_k(const u16* __restrict__ A,
            const u16* W0, const u16* W1, const u16* W2,
            const float* b0, const float* b1, const float* b2,
            void* o0, void* o1, void* o2,
            int L, int m0, int m1, int m2, int posoff,
            const float* __restrict__ cosT, const float* __restrict__ sinT)
{
  __shared__ __align__(16) u16 As[2 * 4096];
  __shared__ __align__(16) u16 Bs[2 * 4096];
  int bx, by, bz;
  swz_block(bx, by, bz);
  const u16* Wt = (bz == 0) ? W0 : ((bz == 1) ? W1 : W2);
  const float* bias = (bz == 0) ? b0 : ((bz == 1) ? b1 : b2);
  void* outp = (bz == 0) ? o0 : ((bz == 1) ? o1 : o2);
  int mode = (bz == 0) ? m0 : ((bz == 1) ? m1 : m2);
  int rowBase = by * 128, colBase = bx * 128;
  int lane = threadIdx.x & 63, w = threadIdx.x >> 6;

  f32x4 acc[4][4] = {};
  gemm_core(A, Wt, rowBase, colBase, lane, w, As, Bs, acc);
  gemm_epilogue(acc, mode, outp, bias, rowBase, colBase, L, posoff, lane, w, cosT, sinT);
}

// ---------- attention helpers ----------
__device__ __forceinline__ void loadq(const u16* qrow, float* qf) {
  const uint4* qp = (const uint4*)qrow;
#pragma unroll
  for (int c = 0; c < 8; ++c) {
    uint4 u = qp[c];
    up2(u.x, qf[c * 8 + 0], qf[c * 8 + 1]);
    up2(u.y, qf[c * 8 + 2], qf[c * 8 + 3]);
    up2(u.z, qf[c * 8 + 4], qf[c * 8 + 5]);
    up2(u.w, qf[c * 8 + 6], qf[c * 8 + 7]);
  }
}
__device__ __forceinline__ float dot64(const float* qf, const u16* krow) {
  const uint4* kp = (const uint4*)krow;
  float s = 0.f;
#pragma unroll
  for (int c = 0; c < 8; ++c) {
    uint4 u = kp[c];
    float a0, a1, a2, a3, a4, a5, a6, a7;
    up2(u.x, a0, a1); up2(u.y, a2, a3); up2(u.z, a4, a5); up2(u.w, a6, a7);
    s += qf[c * 8 + 0] * a0 + qf[c * 8 + 1] * a1 + qf[c * 8 + 2] * a2 + qf[c * 8 + 3] * a3
       + qf[c * 8 + 4] * a4 + qf[c * 8 + 5] * a5 + qf[c * 8 + 6] * a6 + qf[c * 8 + 7] * a7;
  }
  return s;
}

// ---------- stage-1 attention: one query per wave ----------
__global__ __launch_bounds__(256)
void attn1_k(const u16* __restrict__ Qs, const u16* __restrict__ Ks,
             const u16* __restrict__ Vs, const u16* __restrict__ Kr,
             const u16* __restrict__ Vr, u16* __restrict__ outA)
{
  int gw = blockIdx.x * 4 + (threadIdx.x >> 6);
  int bh = gw >> 6, qi = gw & 63;
  int b = bh >> 4, h = bh & 15;
  int lane = threadIdx.x & 63;
  const u16* qB = Qs + (size_t)bh * SLEN * HDIM;
  const u16* kS = Ks + (size_t)bh * SLEN * HDIM;
  const u16* vS = Vs + (size_t)bh * SLEN * HDIM;
  const u16* kR = Kr + (size_t)bh * RLEN * HDIM;
  const u16* vR = Vr + (size_t)bh * RLEN * HDIM;

  float qf[64];
  loadq(qB + qi * HDIM, qf);
  bool v1 = (lane <= qi);
  bool v2 = (lane < 32);
  float s1 = v1 ? dot64(qf, kS + lane * HDIM) : 0.f;
  float s2 = v2 ? dot64(qf, kR + (qi * 32 + lane) * HDIM) : 0.f;
  float sc1 = v1 ? s1 * 0.125f : -1e30f;
  float sc2 = v2 ? s2 * 0.125f : -1e30f;
  float mx = fmaxf(sc1, sc2);
#pragma unroll
  for (int off = 32; off; off >>= 1) mx = fmaxf(mx, __shfl_xor(mx, off));
  float e1 = v1 ? __expf(sc1 - mx) : 0.f;
  float e2 = v2 ? __expf(sc2 - mx) : 0.f;
  float sm = e1 + e2;
#pragma unroll
  for (int off = 32; off; off >>= 1) sm += __shfl_xor(sm, off);
  float inv = 1.f / sm;

  float a0 = 0.f, a1 = 0.f, a2 = 0.f, a3 = 0.f;
  const u16* vrow = vR + (size_t)qi * 32 * HDIM + lane;
#pragma unroll
  for (int j = 0; j < 64; j += 4) {
    a0 += __shfl(e1, j + 0) * bf2f(vS[(j + 0) * HDIM + lane]);
    a1 += __shfl(e1, j + 1) * bf2f(vS[(j + 1) * HDIM + lane]);
    a2 += __shfl(e1, j + 2) * bf2f(vS[(j + 2) * HDIM + lane]);
    a3 += __shfl(e1, j + 3) * bf2f(vS[(j + 3) * HDIM + lane]);
  }
#pragma unroll
  for (int j = 0; j < 32; j += 4) {
    a0 += __shfl(e2, j + 0) * bf2f(vrow[(j + 0) * HDIM]);
    a1 += __shfl(e2, j + 1) * bf2f(vrow[(j + 1) * HDIM]);
    a2 += __shfl(e2, j + 2) * bf2f(vrow[(j + 2) * HDIM]);
    a3 += __shfl(e2, j + 3) * bf2f(vrow[(j + 3) * HDIM]);
  }
  float accv = (a0 + a1) + (a2 + a3);
  outA[((size_t)(b * SLEN + qi)) * EMBED + h * HDIM + lane] = f2bf(accv * inv);
}

// ---------- stage-2 attention: MFMA per (b,h,bar) block ----------
__global__ __launch_bounds__(256)
void attn2_k(const u16* __restrict__ Qr, const u16* __restrict__ Kr,
             const u16* __restrict__ Vr, const u16* __restrict__ Ks2,
             const u16* __restrict__ Vs2, u16* __restrict__ outA)
{
  __shared__ __align__(16) float Sf[32][104];
  __shared__ __align__(16) u16 Pb[32][104];
  __shared__ __align__(16) u16 Vt[64][104];

  int bar = blockIdx.x, bh = blockIdx.y;
  int b = bh >> 4, h = bh & 15;
  int nS = bar + 1;
  int tid = threadIdx.x, lane = tid & 63, w = tid >> 6;
  int l15 = lane & 15, lg = lane >> 4;

  const u16* qB = Qr + ((size_t)bh * RLEN + bar * 32) * HDIM;
  const u16* kS = Ks2 + (size_t)bh * SLEN * HDIM;
  const u16* kR = Kr + ((size_t)bh * RLEN + bar * 32) * HDIM;
  const u16* vS = Vs2 + (size_t)bh * SLEN * HDIM;
  const u16* vR = Vr + ((size_t)bh * RLEN + bar * 32) * HDIM;

  for (int e = tid; e < 96 * 64; e += 256) {
    int key = e >> 6, d = e & 63;
    Vt[d][key] = (key < 64) ? vS[key * 64 + d] : vR[(key - 64) * 64 + d];
  }

#pragma unroll
  for (int i = 0; i < 3; ++i) {
    int t = w * 3 + i, r = t / 6, c = t % 6;
    const u16* arow = qB + (r * 16 + l15) * 64 + lg * 8;
    const u16* brow = (c < 4) ? (kS + (c * 16 + l15) * 64 + lg * 8)
                              : (kR + ((c - 4) * 16 + l15) * 64 + lg * 8);
    f32x4 acc = {};
    acc = __builtin_amdgcn_mfma_f32_16x16x32_bf16(*(const short8*)arow,
                                                  *(const short8*)brow, acc, 0, 0, 0);
    acc = __builtin_amdgcn_mfma_f32_16x16x32_bf16(*(const short8*)(arow + 32),
                                                  *(const short8*)(brow + 32), acc, 0, 0, 0);
#pragma unroll
    for (int j = 0; j < 4; ++j)
      Sf[r * 16 + lg * 4 + j][c * 16 + l15] = acc[j] * 0.125f;
  }
  __syncthreads();

  {
    int r = w * 8 + (lane >> 3), sub = lane & 7;
    float vals[12];
    float mx = -1e30f;
#pragma unroll
    for (int j = 0; j < 12; ++j) {
      int c = sub + 8 * j;
      bool valid = (c < nS) || (c >= 64 && c < 96 && (c - 64) <= r);
      float v = valid ? Sf[r][c] : -1e30f;
      vals[j] = v;
      mx = fmaxf(mx, v);
    }
#pragma unroll
    for (int off = 1; off < 8; off <<= 1) mx = fmaxf(mx, __shfl_xor(mx, off));
    float sm = 0.f;
#pragma unroll
    for (int j = 0; j < 12; ++j) {
      vals[j] = __expf(vals[j] - mx);
      sm += vals[j];
    }
#pragma unroll
    for (int off = 1; off < 8; off <<= 1) sm += __shfl_xor(sm, off);
    float inv = 1.f / sm;
#pragma unroll
    for (int j = 0; j < 12; ++j) {
      int c = sub + 8 * j;
      Pb[r][c] = f2bf(vals[j] * inv);
    }
  }
  __syncthreads();

#pragma unroll
  for (int i = 0; i < 2; ++i) {
    int t = w * 2 + i, r = t >> 2, dc = t & 3;
    f32x4 acc = {};
#pragma unroll
    for (int ks = 0; ks < 3; ++ks) {
      short8 a = *(const short8*)&Pb[r * 16 + l15][ks * 32 + lg * 8];
      short8 bb = *(const short8*)&Vt[dc * 16 + l15][ks * 32 + lg * 8];
      acc = __builtin_amdgcn_mfma_f32_16x16x32_bf16(a, bb, acc, 0, 0, 0);
    }
    int d = dc * 16 + l15;
#pragma unroll
    for (int j = 0; j < 4; ++j) {
      int qq = r * 16 + lg * 4 + j;
      int tt = bar * 32 + qq;
      outA[((size_t)(b * RLEN + tt)) * EMBED + h * 64 + d] = f2bf(acc[j]);
    }
  }
}

// ---------- host ----------
extern "C" void kernel_launch(void* const* d_in, const int* in_sizes, int n_in,
                              void* d_out, int out_size, void* d_ws, size_t ws_size,
                              hipStream_t stream) {
  const float* sum_x = (const float*)d_in[0];
  const float* reg_x = (const float*)d_in[1];
  const float* W[10]; const float* Bv[10];
  for (int i = 0; i < 10; ++i) {
    W[i] = (const float*)d_in[4 + 2 * i];
    Bv[i] = (const float*)d_in[5 + 2 * i];
  }

  char* ws = (char*)d_ws;
  size_t off = 0;
  auto alloc = [&](size_t bytes) -> void* {
    void* p = ws + off;
    off += (bytes + 255) & ~(size_t)255;
    return p;
  };

  const size_t SX = (size_t)NBATCH * SLEN * EMBED;
  const size_t RX = (size_t)NBATCH * RLEN * EMBED;

  float* cosT = (float*)alloc((size_t)TOTKV * 32 * 4);
  float* sinT = (float*)alloc((size_t)TOTKV * 32 * 4);
  u16* sxb = (u16*)alloc(SX * 2);
  u16* rxb = (u16*)alloc(RX * 2);
  u16* Wt  = (u16*)alloc((size_t)10 * EMBED * EMBED * 2);
  u16* Qs = (u16*)alloc(SX * 2);
  u16* Ks = (u16*)alloc(SX * 2);
  u16* Vs = (u16*)alloc(SX * 2);
  u16* Qr = (u16*)alloc(RX * 2);
  u16* Kr = (u16*)alloc(RX * 2);
  u16* Vr = (u16*)alloc(RX * 2);
  u16* sattn = (u16*)alloc(SX * 2);
  u16* Ks2 = (u16*)alloc(SX * 2);
  u16* Vs2 = (u16*)alloc(SX * 2);
  u16* rattn = (u16*)alloc(RX * 2);
  (void)ws_size; (void)in_sizes; (void)n_in; (void)out_size;

  rope_table_k<<<(TOTKV * 32 + 255) / 256, 256, 0, stream>>>(cosT, sinT);
  f2bf_k<<<(int)(SX / 4 + 255) / 256, 256, 0, stream>>>(sum_x, sxb, (int)SX);
  f2bf_k<<<(int)(RX / 4 + 255) / 256, 256, 0, stream>>>(reg_x, rxb, (int)RX);
  WSrc wsrc;
  for (int i = 0; i < 10; ++i) wsrc.p[i] = W[i];
  transpose_w_k<<<dim3(16, 16, 10), 256, 0, stream>>>(wsrc, Wt);

  B10 biases;
  for (int i = 0; i < 10; ++i) biases.p[i] = Bv[i];

#define WT(i) (Wt + (size_t)(i) * EMBED * EMBED)
  // fused sum+reg QKV GEMM (+RoPE on q,k)
  qkv_gemm_k<<<dim3(8, 33, 3), 256, 0, stream>>>(rxb, sxb, Wt, biases,
      Qs, Ks, Vs, Qr, Kr, Vr, cosT, sinT);
  // stage-1 attention -> sattn
  attn1_k<<<512, 256, 0, stream>>>(Qs, Ks, Vs, Kr, Vr, sattn);
  // fused k2/v2 projections + summary out-projection
  float* outS = (float*)d_out;
  float* outR = outS + SX;
  gemm_k<<<dim3(8, 1, 3), 256, 0, stream>>>(sattn, WT(8), WT(9), WT(3),
      Bv[8], Bv[9], Bv[3], Ks2, Vs2, outS, SLEN, 1, 1, 2, 0, cosT, sinT);
  // stage-2 attention -> rattn
  attn2_k<<<dim3(64, 32), 256, 0, stream>>>(Qr, Kr, Vr, Ks2, Vs2, rattn);
  // regular out-projection -> d_out
  gemm_k<<<dim3(8, 32, 1), 256, 0, stream>>>(rattn, WT(7), WT(7), WT(7),
      Bv[7], Bv[7], Bv[7], outR, outR, outR, RLEN, 2, 2, 2, 0, cosT, sinT);
#undef WT
}

// Round 4
// 167.174 us; speedup vs baseline: 3.7003x; 1.0648x over previous
//
#include <hip/hip_runtime.h>
#include <stdint.h>

typedef unsigned short u16;
typedef unsigned int u32;
typedef __attribute__((ext_vector_type(8))) short short8;
typedef __attribute__((ext_vector_type(4))) float f32x4;

#define EMBED 1024
#define HEADS 16
#define HDIM 64
#define NBATCH 2
#define SLEN 64
#define RLEN 2048
#define TOTKV (SLEN + RLEN)   // 2112

struct B10 { const float* p[10]; };

// ---------- small helpers ----------
__device__ __forceinline__ float bf2f(u16 u) {
  union { u32 i; float f; } v; v.i = ((u32)u) << 16; return v.f;
}
__device__ __forceinline__ u16 f2bf(float f) {
  union { float f; u32 i; } v; v.f = f;
  return (u16)((v.i + 0x7fffu + ((v.i >> 16) & 1u)) >> 16);  // RNE
}
__device__ __forceinline__ void up2(u32 u, float& a, float& b) {
  union { u32 i; float f; } x, y;
  x.i = u << 16; y.i = u & 0xffff0000u;
  a = x.f; b = y.f;
}
__device__ __forceinline__ void gload16(const void* g, void* l) {
  __builtin_amdgcn_global_load_lds((const __attribute__((address_space(1))) u32*)g,
                                   (__attribute__((address_space(3))) u32*)l, 16, 0, 0);
}

#define VMW4 asm volatile("s_waitcnt vmcnt(4)" ::: "memory")
#define VMW0 asm volatile("s_waitcnt vmcnt(0)" ::: "memory")
#define SBAR __builtin_amdgcn_s_barrier()

// XCD-aware bijective swizzle of linear block id (total % 8 == 0 assumed).
__device__ __forceinline__ void swz_block(int& bx, int& by, int& bz) {
  int gx = gridDim.x, gy = gridDim.y, gz = gridDim.z;
  int total = gx * gy * gz;
  int l = blockIdx.x + gx * (blockIdx.y + gy * blockIdx.z);
  if (total & 7) { bx = blockIdx.x; by = blockIdx.y; bz = blockIdx.z; return; }
  int nl = (l & 7) * (total >> 3) + (l >> 3);
  bx = nl % gx; int t = nl / gx; by = t % gy; bz = t / gy;
}

// ---------- RoPE table ----------
__global__ void rope_table_k(float* __restrict__ cosT, float* __restrict__ sinT) {
  int idx = blockIdx.x * blockDim.x + threadIdx.x;
  if (idx >= TOTKV * 32) return;
  int pos = idx >> 5, i = idx & 31;
  float inv = powf(10000.0f, -(float)i / 32.0f);
  float a = (float)pos * inv;
  float s, c;
  sincosf(a, &s, &c);
  cosT[idx] = c; sinT[idx] = s;
}

// ---------- f32 -> bf16 convert ----------
__global__ void f2bf_k(const float* __restrict__ src, u16* __restrict__ dst, int n) {
  int i = (blockIdx.x * blockDim.x + threadIdx.x) * 4;
  if (i >= n) return;
  float4 v = *(const float4*)(src + i);
  u32 lo = (u32)f2bf(v.x) | ((u32)f2bf(v.y) << 16);
  u32 hi = (u32)f2bf(v.z) | ((u32)f2bf(v.w) << 16);
  uint2 o; o.x = lo; o.y = hi;
  *(uint2*)(dst + i) = o;
}

// ---------- weight transpose: W[k][n] f32 -> Wt[n][k] bf16 ----------
struct WSrc { const float* p[10]; };
__global__ void transpose_w_k(WSrc wsrc, u16* __restrict__ dst) {
  __shared__ float tile[64][65];
  const float* src = wsrc.p[blockIdx.z];
  u16* out = dst + (size_t)blockIdx.z * (EMBED * (size_t)EMBED);
  int t = threadIdx.x;
  int k0 = blockIdx.y * 64, n0 = blockIdx.x * 64;
  int r0 = t >> 4, c0 = (t & 15) * 4;
#pragma unroll
  for (int i = 0; i < 4; ++i) {
    int r = i * 16 + r0;
    float4 v = *(const float4*)(src + (size_t)(k0 + r) * EMBED + n0 + c0);
    tile[r][c0] = v.x; tile[r][c0 + 1] = v.y; tile[r][c0 + 2] = v.z; tile[r][c0 + 3] = v.w;
  }
  __syncthreads();
#pragma unroll
  for (int i = 0; i < 4; ++i) {
    int n = i * 16 + r0;
    uint2 o;
    o.x = (u32)f2bf(tile[c0][n]) | ((u32)f2bf(tile[c0 + 1][n]) << 16);
    o.y = (u32)f2bf(tile[c0 + 2][n]) | ((u32)f2bf(tile[c0 + 3][n]) << 16);
    *(uint2*)(out + (size_t)(n0 + n) * EMBED + k0 + c0) = o;
  }
}

// ---------- shared GEMM core: 128x128 tile, BK=32, 3-buffer counted-vmcnt pipeline ----------
// As/Bs: u16[3*4096] each. K fixed at 1024 (32 steps).
__device__ __forceinline__ void gemm_core(const u16* __restrict__ A, const u16* __restrict__ Wt,
                                          int rowBase, int colBase, int lane, int w,
                                          u16* As, u16* Bs, f32x4 (&acc)[4][4]) {
  int wr = w >> 1, wc = w & 1;
  int lr = lane >> 2, l4 = lane & 3;
  const u16* srcA0 = A + (size_t)(rowBase + w * 16 + lr) * EMBED + l4 * 8;
  const u16* srcA1 = srcA0 + 64 * EMBED;
  const u16* srcB0 = Wt + (size_t)(colBase + w * 16 + lr) * EMBED + l4 * 8;
  const u16* srcB1 = srcB0 + 64 * EMBED;
  u16* dstA = As + w * 512;
  u16* dstB = Bs + w * 512;
  int aoff = (lane & 15) * 32 + (lane >> 4) * 8;
  const u16* fA = As + wr * 2048 + aoff;
  const u16* fB = Bs + wc * 2048 + aoff;

#define STAGE(T, BUF) do { \
    gload16(srcA0 + (T) * 32, dstA + (BUF) * 4096); \
    gload16(srcA1 + (T) * 32, dstA + (BUF) * 4096 + 2048); \
    gload16(srcB0 + (T) * 32, dstB + (BUF) * 4096); \
    gload16(srcB1 + (T) * 32, dstB + (BUF) * 4096 + 2048); \
  } while (0)

  auto compute = [&](int buf) {
    const u16* fAc = fA + buf * 4096;
    const u16* fBc = fB + buf * 4096;
    short8 af[4], bfv[4];
#pragma unroll
    for (int mi = 0; mi < 4; ++mi) af[mi] = *(const short8*)(fAc + mi * 512);
#pragma unroll
    for (int ni = 0; ni < 4; ++ni) bfv[ni] = *(const short8*)(fBc + ni * 512);
#pragma unroll
    for (int mi = 0; mi < 4; ++mi)
#pragma unroll
      for (int ni = 0; ni < 4; ++ni)
        acc[mi][ni] = __builtin_amdgcn_mfma_f32_16x16x32_bf16(af[mi], bfv[ni], acc[mi][ni], 0, 0, 0);
  };

  // prologue: stages S0,S1 in flight; wait own S0, join.
  STAGE(0, 0);
  STAGE(1, 1);
  VMW4;
  SBAR;

  // main loop: 30 compute steps (k=0..29), 3-step unrolled so buffer ids are static.
  // Invariant at each barrier: S(t+1) landed for all waves; S(t+2) still in flight.
#pragma unroll 1
  for (int tt = 0; tt < 10; ++tt) {
    int t = tt * 3;
    STAGE(t + 2, 2); compute(0); VMW4; SBAR;
    STAGE(t + 3, 0); compute(1); VMW4; SBAR;
    STAGE(t + 4, 1); compute(2); VMW4; SBAR;
  }
  // tail: k=30 (buf0, S30 landed at last barrier), then drain S31, k=31 (buf1).
  compute(0);
  VMW0;
  SBAR;
  compute(1);
#undef STAGE
}

// mode 0: bf16 headsplit + rope; mode 1: bf16 headsplit; mode 2: f32 row-major
__device__ __forceinline__ void gemm_epilogue(f32x4 (&acc)[4][4], int mode, void* outp,
                                              const float* bias, int rowBase, int colBase,
                                              int L, int posoff, int lane, int w,
                                              const float* cosT, const float* sinT) {
  int wr = w >> 1, wc = w & 1;
  int c15 = lane & 15, rgrp = (lane >> 4) * 4;
  if (mode == 2) {
    float* out = (float*)outp;
#pragma unroll
    for (int mi = 0; mi < 4; ++mi)
#pragma unroll
      for (int r = 0; r < 4; ++r) {
        int m = rowBase + wr * 64 + mi * 16 + rgrp + r;
#pragma unroll
        for (int ni = 0; ni < 4; ++ni) {
          int n = colBase + wc * 64 + ni * 16 + c15;
          out[(size_t)m * EMBED + n] = acc[mi][ni][r] + bias[n];
        }
      }
  } else {
    u16* out = (u16*)outp;
    int h = (colBase >> 6) + wc;
    bool dorope = (mode == 0);
#pragma unroll
    for (int mi = 0; mi < 4; ++mi)
#pragma unroll
      for (int r = 0; r < 4; ++r) {
        int m = rowBase + wr * 64 + mi * 16 + rgrp + r;
        int bidx = (m >= L) ? 1 : 0;
        int l = m - bidx * L;
        size_t obase = ((size_t)(bidx * HEADS + h) * L + l) * HDIM;
        if (dorope) {
          int pos = posoff + l;
#pragma unroll
          for (int ni = 0; ni < 2; ++ni) {
            int d = ni * 16 + c15;
            float c = cosT[pos * 32 + d], s = sinT[pos * 32 + d];
            float x0 = acc[mi][ni][r] + bias[h * 64 + d];
            float x2 = acc[mi][ni + 2][r] + bias[h * 64 + d + 32];
            out[obase + d]      = f2bf(x0 * c - x2 * s);
            out[obase + d + 32] = f2bf(x2 * c + x0 * s);
          }
        } else {
#pragma unroll
          for (int ni = 0; ni < 4; ++ni) {
            int d = ni * 16 + c15;
            out[obase + d] = f2bf(acc[mi][ni][r] + bias[h * 64 + d]);
          }
        }
      }
  }
}

// ---------- fused QKV GEMM: grid (8, 33, 3); by==32 -> summary side ----------
__global__ __launch_bounds__(256)
void qkv_gemm_k(const u16* __restrict__ rxb, const u16* __restrict__ sxb,
                const u16* __restrict__ Wt_all, B10 biases,
                u16* Qs, u16* Ks, u16* Vs, u16* Qr, u16* Kr, u16* Vr,
                const float* __restrict__ cosT, const float* __restrict__ sinT)
{
  __shared__ __align__(16) u16 As[3 * 4096];
  __shared__ __align__(16) u16 Bs[3 * 4096];
  int bx, by, bz;
  swz_block(bx, by, bz);

  bool issum = (by == 32);
  const u16* A = issum ? sxb : rxb;
  int rowBase = issum ? 0 : by * 128;
  int L = issum ? SLEN : RLEN;
  int posoff = issum ? 0 : SLEN;
  int widx = issum ? bz : 4 + bz;
  const u16* Wt = Wt_all + (size_t)widx * EMBED * EMBED;
  const float* bias = biases.p[widx];
  u16* out = issum ? (bz == 0 ? Qs : (bz == 1 ? Ks : Vs))
                   : (bz == 0 ? Qr : (bz == 1 ? Kr : Vr));
  int mode = (bz < 2) ? 0 : 1;
  int colBase = bx * 128;
  int lane = threadIdx.x & 63, w = threadIdx.x >> 6;

  f32x4 acc[4][4] = {};
  gemm_core(A, Wt, rowBase, colBase, lane, w, As, Bs, acc);
  gemm_epilogue(acc, mode, out, bias, rowBase, colBase, L, posoff, lane, w, cosT, sinT);
}

// ---------- generic GEMM: z selects (W, bias, out, mode) ----------
__global__ __launch_bounds__(256)
void gemm_k(const u16* __restrict__ A,
            const u16* W0, const u16* W1, const u16* W2,
            const float* b0, const float* b1, const float* b2,
            void* o0, void* o1, void* o2,
            int L, int m0, int m1, int m2, int posoff,
            const float* __restrict__ cosT, const float* __restrict__ sinT)
{
  __shared__ __align__(16) u16 As[3 * 4096];
  __shared__ __align__(16) u16 Bs[3 * 4096];
  int bx, by, bz;
  swz_block(bx, by, bz);
  const u16* Wt = (bz == 0) ? W0 : ((bz == 1) ? W1 : W2);
  const float* bias = (bz == 0) ? b0 : ((bz == 1) ? b1 : b2);
  void* outp = (bz == 0) ? o0 : ((bz == 1) ? o1 : o2);
  int mode = (bz == 0) ? m0 : ((bz == 1) ? m1 : m2);
  int rowBase = by * 128, colBase = bx * 128;
  int lane = threadIdx.x & 63, w = threadIdx.x >> 6;

  f32x4 acc[4][4] = {};
  gemm_core(A, Wt, rowBase, colBase, lane, w, As, Bs, acc);
  gemm_epilogue(acc, mode, outp, bias, rowBase, colBase, L, posoff, lane, w, cosT, sinT);
}

// ---------- attention helpers ----------
__device__ __forceinline__ void loadq(const u16* qrow, float* qf) {
  const uint4* qp = (const uint4*)qrow;
#pragma unroll
  for (int c = 0; c < 8; ++c) {
    uint4 u = qp[c];
    up2(u.x, qf[c * 8 + 0], qf[c * 8 + 1]);
    up2(u.y, qf[c * 8 + 2], qf[c * 8 + 3]);
    up2(u.z, qf[c * 8 + 4], qf[c * 8 + 5]);
    up2(u.w, qf[c * 8 + 6], qf[c * 8 + 7]);
  }
}
__device__ __forceinline__ float dot64(const float* qf, const u16* krow) {
  const uint4* kp = (const uint4*)krow;
  float s = 0.f;
#pragma unroll
  for (int c = 0; c < 8; ++c) {
    uint4 u = kp[c];
    float a0, a1, a2, a3, a4, a5, a6, a7;
    up2(u.x, a0, a1); up2(u.y, a2, a3); up2(u.z, a4, a5); up2(u.w, a6, a7);
    s += qf[c * 8 + 0] * a0 + qf[c * 8 + 1] * a1 + qf[c * 8 + 2] * a2 + qf[c * 8 + 3] * a3
       + qf[c * 8 + 4] * a4 + qf[c * 8 + 5] * a5 + qf[c * 8 + 6] * a6 + qf[c * 8 + 7] * a7;
  }
  return s;
}

// ---------- stage-1 attention: one query per wave ----------
__global__ __launch_bounds__(256)
void attn1_k(const u16* __restrict__ Qs, const u16* __restrict__ Ks,
             const u16* __restrict__ Vs, const u16* __restrict__ Kr,
             const u16* __restrict__ Vr, u16* __restrict__ outA)
{
  int gw = blockIdx.x * 4 + (threadIdx.x >> 6);
  int bh = gw >> 6, qi = gw & 63;
  int b = bh >> 4, h = bh & 15;
  int lane = threadIdx.x & 63;
  const u16* qB = Qs + (size_t)bh * SLEN * HDIM;
  const u16* kS = Ks + (size_t)bh * SLEN * HDIM;
  const u16* vS = Vs + (size_t)bh * SLEN * HDIM;
  const u16* kR = Kr + (size_t)bh * RLEN * HDIM;
  const u16* vR = Vr + (size_t)bh * RLEN * HDIM;

  float qf[64];
  loadq(qB + qi * HDIM, qf);
  bool v1 = (lane <= qi);
  bool v2 = (lane < 32);
  float s1 = v1 ? dot64(qf, kS + lane * HDIM) : 0.f;
  float s2 = v2 ? dot64(qf, kR + (qi * 32 + lane) * HDIM) : 0.f;
  float sc1 = v1 ? s1 * 0.125f : -1e30f;
  float sc2 = v2 ? s2 * 0.125f : -1e30f;
  float mx = fmaxf(sc1, sc2);
#pragma unroll
  for (int off = 32; off; off >>= 1) mx = fmaxf(mx, __shfl_xor(mx, off));
  float e1 = v1 ? __expf(sc1 - mx) : 0.f;
  float e2 = v2 ? __expf(sc2 - mx) : 0.f;
  float sm = e1 + e2;
#pragma unroll
  for (int off = 32; off; off >>= 1) sm += __shfl_xor(sm, off);
  float inv = 1.f / sm;

  float a0 = 0.f, a1 = 0.f, a2 = 0.f, a3 = 0.f;
  const u16* vrow = vR + (size_t)qi * 32 * HDIM + lane;
#pragma unroll
  for (int j = 0; j < 64; j += 4) {
    a0 += __shfl(e1, j + 0) * bf2f(vS[(j + 0) * HDIM + lane]);
    a1 += __shfl(e1, j + 1) * bf2f(vS[(j + 1) * HDIM + lane]);
    a2 += __shfl(e1, j + 2) * bf2f(vS[(j + 2) * HDIM + lane]);
    a3 += __shfl(e1, j + 3) * bf2f(vS[(j + 3) * HDIM + lane]);
  }
#pragma unroll
  for (int j = 0; j < 32; j += 4) {
    a0 += __shfl(e2, j + 0) * bf2f(vrow[(j + 0) * HDIM]);
    a1 += __shfl(e2, j + 1) * bf2f(vrow[(j + 1) * HDIM]);
    a2 += __shfl(e2, j + 2) * bf2f(vrow[(j + 2) * HDIM]);
    a3 += __shfl(e2, j + 3) * bf2f(vrow[(j + 3) * HDIM]);
  }
  float accv = (a0 + a1) + (a2 + a3);
  outA[((size_t)(b * SLEN + qi)) * EMBED + h * HDIM + lane] = f2bf(accv * inv);
}

// ---------- stage-2 attention: MFMA per (b,h,bar) block ----------
__global__ __launch_bounds__(256)
void attn2_k(const u16* __restrict__ Qr, const u16* __restrict__ Kr,
             const u16* __restrict__ Vr, const u16* __restrict__ Ks2,
             const u16* __restrict__ Vs2, u16* __restrict__ outA)
{
  __shared__ __align__(16) float Sf[32][104];
  __shared__ __align__(16) u16 Pb[32][104];
  __shared__ __align__(16) u16 Vt[64][104];

  int bar = blockIdx.x, bh = blockIdx.y;
  int b = bh >> 4, h = bh & 15;
  int nS = bar + 1;
  int tid = threadIdx.x, lane = tid & 63, w = tid >> 6;
  int l15 = lane & 15, lg = lane >> 4;

  const u16* qB = Qr + ((size_t)bh * RLEN + bar * 32) * HDIM;
  const u16* kS = Ks2 + (size_t)bh * SLEN * HDIM;
  const u16* kR = Kr + ((size_t)bh * RLEN + bar * 32) * HDIM;
  const u16* vS = Vs2 + (size_t)bh * SLEN * HDIM;
  const u16* vR = Vr + ((size_t)bh * RLEN + bar * 32) * HDIM;

  for (int e = tid; e < 96 * 64; e += 256) {
    int key = e >> 6, d = e & 63;
    Vt[d][key] = (key < 64) ? vS[key * 64 + d] : vR[(key - 64) * 64 + d];
  }

#pragma unroll
  for (int i = 0; i < 3; ++i) {
    int t = w * 3 + i, r = t / 6, c = t % 6;
    const u16* arow = qB + (r * 16 + l15) * 64 + lg * 8;
    const u16* brow = (c < 4) ? (kS + (c * 16 + l15) * 64 + lg * 8)
                              : (kR + ((c - 4) * 16 + l15) * 64 + lg * 8);
    f32x4 acc = {};
    acc = __builtin_amdgcn_mfma_f32_16x16x32_bf16(*(const short8*)arow,
                                                  *(const short8*)brow, acc, 0, 0, 0);
    acc = __builtin_amdgcn_mfma_f32_16x16x32_bf16(*(const short8*)(arow + 32),
                                                  *(const short8*)(brow + 32), acc, 0, 0, 0);
#pragma unroll
    for (int j = 0; j < 4; ++j)
      Sf[r * 16 + lg * 4 + j][c * 16 + l15] = acc[j] * 0.125f;
  }
  __syncthreads();

  {
    int r = w * 8 + (lane >> 3), sub = lane & 7;
    float vals[12];
    float mx = -1e30f;
#pragma unroll
    for (int j = 0; j < 12; ++j) {
      int c = sub + 8 * j;
      bool valid = (c < nS) || (c >= 64 && c < 96 && (c - 64) <= r);
      float v = valid ? Sf[r][c] : -1e30f;
      vals[j] = v;
      mx = fmaxf(mx, v);
    }
#pragma unroll
    for (int off = 1; off < 8; off <<= 1) mx = fmaxf(mx, __shfl_xor(mx, off));
    float sm = 0.f;
#pragma unroll
    for (int j = 0; j < 12; ++j) {
      vals[j] = __expf(vals[j] - mx);
      sm += vals[j];
    }
#pragma unroll
    for (int off = 1; off < 8; off <<= 1) sm += __shfl_xor(sm, off);
    float inv = 1.f / sm;
#pragma unroll
    for (int j = 0; j < 12; ++j) {
      int c = sub + 8 * j;
      Pb[r][c] = f2bf(vals[j] * inv);
    }
  }
  __syncthreads();

#pragma unroll
  for (int i = 0; i < 2; ++i) {
    int t = w * 2 + i, r = t >> 2, dc = t & 3;
    f32x4 acc = {};
#pragma unroll
    for (int ks = 0; ks < 3; ++ks) {
      short8 a = *(const short8*)&Pb[r * 16 + l15][ks * 32 + lg * 8];
      short8 bb = *(const short8*)&Vt[dc * 16 + l15][ks * 32 + lg * 8];
      acc = __builtin_amdgcn_mfma_f32_16x16x32_bf16(a, bb, acc, 0, 0, 0);
    }
    int d = dc * 16 + l15;
#pragma unroll
    for (int j = 0; j < 4; ++j) {
      int qq = r * 16 + lg * 4 + j;
      int tt = bar * 32 + qq;
      outA[((size_t)(b * RLEN + tt)) * EMBED + h * 64 + d] = f2bf(acc[j]);
    }
  }
}

// ---------- host ----------
extern "C" void kernel_launch(void* const* d_in, const int* in_sizes, int n_in,
                              void* d_out, int out_size, void* d_ws, size_t ws_size,
                              hipStream_t stream) {
  const float* sum_x = (const float*)d_in[0];
  const float* reg_x = (const float*)d_in[1];
  const float* W[10]; const float* Bv[10];
  for (int i = 0; i < 10; ++i) {
    W[i] = (const float*)d_in[4 + 2 * i];
    Bv[i] = (const float*)d_in[5 + 2 * i];
  }

  char* ws = (char*)d_ws;
  size_t off = 0;
  auto alloc = [&](size_t bytes) -> void* {
    void* p = ws + off;
    off += (bytes + 255) & ~(size_t)255;
    return p;
  };

  const size_t SX = (size_t)NBATCH * SLEN * EMBED;
  const size_t RX = (size_t)NBATCH * RLEN * EMBED;

  float* cosT = (float*)alloc((size_t)TOTKV * 32 * 4);
  float* sinT = (float*)alloc((size_t)TOTKV * 32 * 4);
  u16* sxb = (u16*)alloc(SX * 2);
  u16* rxb = (u16*)alloc(RX * 2);
  u16* Wt  = (u16*)alloc((size_t)10 * EMBED * EMBED * 2);
  u16* Qs = (u16*)alloc(SX * 2);
  u16* Ks = (u16*)alloc(SX * 2);
  u16* Vs = (u16*)alloc(SX * 2);
  u16* Qr = (u16*)alloc(RX * 2);
  u16* Kr = (u16*)alloc(RX * 2);
  u16* Vr = (u16*)alloc(RX * 2);
  u16* sattn = (u16*)alloc(SX * 2);
  u16* Ks2 = (u16*)alloc(SX * 2);
  u16* Vs2 = (u16*)alloc(SX * 2);
  u16* rattn = (u16*)alloc(RX * 2);
  (void)ws_size; (void)in_sizes; (void)n_in; (void)out_size;

  rope_table_k<<<(TOTKV * 32 + 255) / 256, 256, 0, stream>>>(cosT, sinT);
  f2bf_k<<<(int)(SX / 4 + 255) / 256, 256, 0, stream>>>(sum_x, sxb, (int)SX);
  f2bf_k<<<(int)(RX / 4 + 255) / 256, 256, 0, stream>>>(reg_x, rxb, (int)RX);
  WSrc wsrc;
  for (int i = 0; i < 10; ++i) wsrc.p[i] = W[i];
  transpose_w_k<<<dim3(16, 16, 10), 256, 0, stream>>>(wsrc, Wt);

  B10 biases;
  for (int i = 0; i < 10; ++i) biases.p[i] = Bv[i];

#define WT(i) (Wt + (size_t)(i) * EMBED * EMBED)
  // fused sum+reg QKV GEMM (+RoPE on q,k)
  qkv_gemm_k<<<dim3(8, 33, 3), 256, 0, stream>>>(rxb, sxb, Wt, biases,
      Qs, Ks, Vs, Qr, Kr, Vr, cosT, sinT);
  // stage-1 attention -> sattn
  attn1_k<<<512, 256, 0, stream>>>(Qs, Ks, Vs, Kr, Vr, sattn);
  // fused k2/v2 projections + summary out-projection
  float* outS = (float*)d_out;
  float* outR = outS + SX;
  gemm_k<<<dim3(8, 1, 3), 256, 0, stream>>>(sattn, WT(8), WT(9), WT(3),
      Bv[8], Bv[9], Bv[3], Ks2, Vs2, outS, SLEN, 1, 1, 2, 0, cosT, sinT);
  // stage-2 attention -> rattn
  attn2_k<<<dim3(64, 32), 256, 0, stream>>>(Qr, Kr, Vr, Ks2, Vs2, rattn);
  // regular out-projection -> d_out
  gemm_k<<<dim3(8, 32, 1), 256, 0, stream>>>(rattn, WT(7), WT(7), WT(7),
      Bv[7], Bv[7], Bv[7], outR, outR, outR, RLEN, 2, 2, 2, 0, cosT, sinT);
#undef WT
}

// Round 5
// 162.242 us; speedup vs baseline: 3.8128x; 1.0304x over previous
//
#include <hip/hip_runtime.h>
#include <stdint.h>

typedef unsigned short u16;
typedef unsigned int u32;
typedef __attribute__((ext_vector_type(8))) short short8;
typedef __attribute__((ext_vector_type(4))) float f32x4;

#define EMBED 1024
#define HEADS 16
#define HDIM 64
#define NBATCH 2
#define SLEN 64
#define RLEN 2048
#define TOTKV (SLEN + RLEN)   // 2112

struct B10 { const float* p[10]; };

// ---------- small helpers ----------
__device__ __forceinline__ float bf2f(u16 u) {
  union { u32 i; float f; } v; v.i = ((u32)u) << 16; return v.f;
}
__device__ __forceinline__ u16 f2bf(float f) {
  union { float f; u32 i; } v; v.f = f;
  return (u16)((v.i + 0x7fffu + ((v.i >> 16) & 1u)) >> 16);  // RNE
}
__device__ __forceinline__ void up2(u32 u, float& a, float& b) {
  union { u32 i; float f; } x, y;
  x.i = u << 16; y.i = u & 0xffff0000u;
  a = x.f; b = y.f;
}
__device__ __forceinline__ void gload16(const void* g, void* l) {
  __builtin_amdgcn_global_load_lds((const __attribute__((address_space(1))) u32*)g,
                                   (__attribute__((address_space(3))) u32*)l, 16, 0, 0);
}

// XCD-aware bijective swizzle of linear block id (total % 8 == 0 assumed).
__device__ __forceinline__ void swz_block(int& bx, int& by, int& bz) {
  int gx = gridDim.x, gy = gridDim.y, gz = gridDim.z;
  int total = gx * gy * gz;
  int l = blockIdx.x + gx * (blockIdx.y + gy * blockIdx.z);
  if (total & 7) { bx = blockIdx.x; by = blockIdx.y; bz = blockIdx.z; return; }
  int nl = (l & 7) * (total >> 3) + (l >> 3);
  bx = nl % gx; int t = nl / gx; by = t % gy; bz = t / gy;
}

// ---------- RoPE table ----------
__global__ void rope_table_k(float* __restrict__ cosT, float* __restrict__ sinT) {
  int idx = blockIdx.x * blockDim.x + threadIdx.x;
  if (idx >= TOTKV * 32) return;
  int pos = idx >> 5, i = idx & 31;
  float inv = powf(10000.0f, -(float)i / 32.0f);
  float a = (float)pos * inv;
  float s, c;
  sincosf(a, &s, &c);
  cosT[idx] = c; sinT[idx] = s;
}

// ---------- f32 -> bf16 convert ----------
__global__ void f2bf_k(const float* __restrict__ src, u16* __restrict__ dst, int n) {
  int i = (blockIdx.x * blockDim.x + threadIdx.x) * 4;
  if (i >= n) return;
  float4 v = *(const float4*)(src + i);
  u32 lo = (u32)f2bf(v.x) | ((u32)f2bf(v.y) << 16);
  u32 hi = (u32)f2bf(v.z) | ((u32)f2bf(v.w) << 16);
  uint2 o; o.x = lo; o.y = hi;
  *(uint2*)(dst + i) = o;
}

// ---------- weight transpose: W[k][n] f32 -> Wt[n][k] bf16 ----------
struct WSrc { const float* p[10]; };
__global__ void transpose_w_k(WSrc wsrc, u16* __restrict__ dst) {
  __shared__ float tile[64][65];
  const float* src = wsrc.p[blockIdx.z];
  u16* out = dst + (size_t)blockIdx.z * (EMBED * (size_t)EMBED);
  int t = threadIdx.x;
  int k0 = blockIdx.y * 64, n0 = blockIdx.x * 64;
  int r0 = t >> 4, c0 = (t & 15) * 4;
#pragma unroll
  for (int i = 0; i < 4; ++i) {
    int r = i * 16 + r0;
    float4 v = *(const float4*)(src + (size_t)(k0 + r) * EMBED + n0 + c0);
    tile[r][c0] = v.x; tile[r][c0 + 1] = v.y; tile[r][c0 + 2] = v.z; tile[r][c0 + 3] = v.w;
  }
  __syncthreads();
#pragma unroll
  for (int i = 0; i < 4; ++i) {
    int n = i * 16 + r0;
    uint2 o;
    o.x = (u32)f2bf(tile[c0][n]) | ((u32)f2bf(tile[c0 + 1][n]) << 16);
    o.y = (u32)f2bf(tile[c0 + 2][n]) | ((u32)f2bf(tile[c0 + 3][n]) << 16);
    *(uint2*)(out + (size_t)(n0 + n) * EMBED + k0 + c0) = o;
  }
}

// ---------- shared GEMM core: 128x128 tile, BK=32, single buffer 2-barrier (proven) ----------
__device__ __forceinline__ void gemm_core(const u16* __restrict__ A, const u16* __restrict__ Wt,
                                          int rowBase, int colBase, int lane, int w,
                                          u16* As, u16* Bs, f32x4 (&acc)[4][4]) {
  int wr = w >> 1, wc = w & 1;
  int lr = lane >> 2, l4 = lane & 3;
  const u16* srcA0 = A + (size_t)(rowBase + w * 16 + lr) * EMBED + l4 * 8;
  const u16* srcA1 = srcA0 + 64 * EMBED;
  const u16* srcB0 = Wt + (size_t)(colBase + w * 16 + lr) * EMBED + l4 * 8;
  const u16* srcB1 = srcB0 + 64 * EMBED;
  u16* dstA = As + w * 512;
  u16* dstB = Bs + w * 512;
  int aoff = (lane & 15) * 32 + (lane >> 4) * 8;
  const u16* fA = As + wr * 2048 + aoff;
  const u16* fB = Bs + wc * 2048 + aoff;

  for (int k0 = 0; k0 < EMBED; k0 += 32) {
    gload16(srcA0 + k0, dstA);
    gload16(srcA1 + k0, dstA + 2048);
    gload16(srcB0 + k0, dstB);
    gload16(srcB1 + k0, dstB + 2048);
    __syncthreads();
    short8 af[4], bfv[4];
#pragma unroll
    for (int mi = 0; mi < 4; ++mi) af[mi] = *(const short8*)(fA + mi * 512);
#pragma unroll
    for (int ni = 0; ni < 4; ++ni) bfv[ni] = *(const short8*)(fB + ni * 512);
#pragma unroll
    for (int mi = 0; mi < 4; ++mi)
#pragma unroll
      for (int ni = 0; ni < 4; ++ni)
        acc[mi][ni] = __builtin_amdgcn_mfma_f32_16x16x32_bf16(af[mi], bfv[ni], acc[mi][ni], 0, 0, 0);
    __syncthreads();
  }
}

// mode 0: bf16 headsplit + rope; mode 1: bf16 headsplit; mode 2: f32 row-major
__device__ __forceinline__ void gemm_epilogue(f32x4 (&acc)[4][4], int mode, void* outp,
                                              const float* bias, int rowBase, int colBase,
                                              int L, int posoff, int lane, int w,
                                              const float* cosT, const float* sinT) {
  int wr = w >> 1, wc = w & 1;
  int c15 = lane & 15, rgrp = (lane >> 4) * 4;
  if (mode == 2) {
    float* out = (float*)outp;
#pragma unroll
    for (int mi = 0; mi < 4; ++mi)
#pragma unroll
      for (int r = 0; r < 4; ++r) {
        int m = rowBase + wr * 64 + mi * 16 + rgrp + r;
#pragma unroll
        for (int ni = 0; ni < 4; ++ni) {
          int n = colBase + wc * 64 + ni * 16 + c15;
          out[(size_t)m * EMBED + n] = acc[mi][ni][r] + bias[n];
        }
      }
  } else {
    u16* out = (u16*)outp;
    int h = (colBase >> 6) + wc;
    bool dorope = (mode == 0);
#pragma unroll
    for (int mi = 0; mi < 4; ++mi)
#pragma unroll
      for (int r = 0; r < 4; ++r) {
        int m = rowBase + wr * 64 + mi * 16 + rgrp + r;
        int bidx = (m >= L) ? 1 : 0;
        int l = m - bidx * L;
        size_t obase = ((size_t)(bidx * HEADS + h) * L + l) * HDIM;
        if (dorope) {
          int pos = posoff + l;
#pragma unroll
          for (int ni = 0; ni < 2; ++ni) {
            int d = ni * 16 + c15;
            float c = cosT[pos * 32 + d], s = sinT[pos * 32 + d];
            float x0 = acc[mi][ni][r] + bias[h * 64 + d];
            float x2 = acc[mi][ni + 2][r] + bias[h * 64 + d + 32];
            out[obase + d]      = f2bf(x0 * c - x2 * s);
            out[obase + d + 32] = f2bf(x2 * c + x0 * s);
          }
        } else {
#pragma unroll
          for (int ni = 0; ni < 4; ++ni) {
            int d = ni * 16 + c15;
            out[obase + d] = f2bf(acc[mi][ni][r] + bias[h * 64 + d]);
          }
        }
      }
  }
}

// ---------- fused QKV GEMM: grid (8, 33, 3); by==32 -> summary side ----------
__global__ __launch_bounds__(256)
void qkv_gemm_k(const u16* __restrict__ rxb, const u16* __restrict__ sxb,
                const u16* __restrict__ Wt_all, B10 biases,
                u16* Qs, u16* Ks, u16* Vs, u16* Qr, u16* Kr, u16* Vr,
                const float* __restrict__ cosT, const float* __restrict__ sinT)
{
  __shared__ __align__(16) u16 As[4096];
  __shared__ __align__(16) u16 Bs[4096];
  int bx, by, bz;
  swz_block(bx, by, bz);

  bool issum = (by == 32);
  const u16* A = issum ? sxb : rxb;
  int rowBase = issum ? 0 : by * 128;
  int L = issum ? SLEN : RLEN;
  int posoff = issum ? 0 : SLEN;
  int widx = issum ? bz : 4 + bz;
  const u16* Wt = Wt_all + (size_t)widx * EMBED * EMBED;
  const float* bias = biases.p[widx];
  u16* out = issum ? (bz == 0 ? Qs : (bz == 1 ? Ks : Vs))
                   : (bz == 0 ? Qr : (bz == 1 ? Kr : Vr));
  int mode = (bz < 2) ? 0 : 1;
  int colBase = bx * 128;
  int lane = threadIdx.x & 63, w = threadIdx.x >> 6;

  f32x4 acc[4][4] = {};
  gemm_core(A, Wt, rowBase, colBase, lane, w, As, Bs, acc);
  gemm_epilogue(acc, mode, out, bias, rowBase, colBase, L, posoff, lane, w, cosT, sinT);
}

// ---------- generic GEMM: z selects (W, bias, out, mode) ----------
__global__ __launch_bounds__(256)
void gemm_k(const u16* __restrict__ A,
            const u16* W0, const u16* W1, const u16* W2,
            const float* b0, const float* b1, const float* b2,
            void* o0, void* o1, void* o2,
            int L, int m0, int m1, int m2, int posoff,
            const float* __restrict__ cosT, const float* __restrict__ sinT)
{
  __shared__ __align__(16) u16 As[4096];
  __shared__ __align__(16) u16 Bs[4096];
  int bx, by, bz;
  swz_block(bx, by, bz);
  const u16* Wt = (bz == 0) ? W0 : ((bz == 1) ? W1 : W2);
  const float* bias = (bz == 0) ? b0 : ((bz == 1) ? b1 : b2);
  void* outp = (bz == 0) ? o0 : ((bz == 1) ? o1 : o2);
  int mode = (bz == 0) ? m0 : ((bz == 1) ? m1 : m2);
  int rowBase = by * 128, colBase = bx * 128;
  int lane = threadIdx.x & 63, w = threadIdx.x >> 6;

  f32x4 acc[4][4] = {};
  gemm_core(A, Wt, rowBase, colBase, lane, w, As, Bs, acc);
  gemm_epilogue(acc, mode, outp, bias, rowBase, colBase, L, posoff, lane, w, cosT, sinT);
}

// ---------- 128x64-tile GEMM (f32 out + bias), for the reg out-projection ----------
// grid (N/64, M/128) = (16, 32) -> 512 blocks (2 blocks/CU for TLP overlap).
__global__ __launch_bounds__(256)
void gemm64_k(const u16* __restrict__ A, const u16* __restrict__ Wt,
              const float* __restrict__ bias, float* __restrict__ out)
{
  __shared__ __align__(16) u16 As[4096];   // 128 x 32
  __shared__ __align__(16) u16 Bs[2048];   // 64 x 32
  int bx, by, bz;
  swz_block(bx, by, bz);
  int rowBase = by * 128, colBase = bx * 64;
  int lane = threadIdx.x & 63, w = threadIdx.x >> 6;
  int lr = lane >> 2, l4 = lane & 3;

  const u16* srcA0 = A + (size_t)(rowBase + w * 16 + lr) * EMBED + l4 * 8;
  const u16* srcA1 = srcA0 + 64 * EMBED;
  const u16* srcB  = Wt + (size_t)(colBase + w * 16 + lr) * EMBED + l4 * 8;
  u16* dstA = As + w * 512;
  u16* dstB = Bs + w * 512;
  int aoff = (lane & 15) * 32 + (lane >> 4) * 8;
  const u16* fA = As + w * 1024 + aoff;   // wave w owns rows w*32..w*32+31
  const u16* fB = Bs + aoff;

  f32x4 acc[2][4] = {};
  for (int k0 = 0; k0 < EMBED; k0 += 32) {
    gload16(srcA0 + k0, dstA);
    gload16(srcA1 + k0, dstA + 2048);
    gload16(srcB + k0, dstB);
    __syncthreads();
    short8 af[2], bfv[4];
#pragma unroll
    for (int mi = 0; mi < 2; ++mi) af[mi] = *(const short8*)(fA + mi * 512);
#pragma unroll
    for (int ni = 0; ni < 4; ++ni) bfv[ni] = *(const short8*)(fB + ni * 512);
#pragma unroll
    for (int mi = 0; mi < 2; ++mi)
#pragma unroll
      for (int ni = 0; ni < 4; ++ni)
        acc[mi][ni] = __builtin_amdgcn_mfma_f32_16x16x32_bf16(af[mi], bfv[ni], acc[mi][ni], 0, 0, 0);
    __syncthreads();
  }

  int c15 = lane & 15, rgrp = (lane >> 4) * 4;
#pragma unroll
  for (int mi = 0; mi < 2; ++mi)
#pragma unroll
    for (int r = 0; r < 4; ++r) {
      int m = rowBase + w * 32 + mi * 16 + rgrp + r;
#pragma unroll
      for (int ni = 0; ni < 4; ++ni) {
        int n = colBase + ni * 16 + c15;
        out[(size_t)m * EMBED + n] = acc[mi][ni][r] + bias[n];
      }
    }
}

// ---------- attention helpers ----------
__device__ __forceinline__ void loadq(const u16* qrow, float* qf) {
  const uint4* qp = (const uint4*)qrow;
#pragma unroll
  for (int c = 0; c < 8; ++c) {
    uint4 u = qp[c];
    up2(u.x, qf[c * 8 + 0], qf[c * 8 + 1]);
    up2(u.y, qf[c * 8 + 2], qf[c * 8 + 3]);
    up2(u.z, qf[c * 8 + 4], qf[c * 8 + 5]);
    up2(u.w, qf[c * 8 + 6], qf[c * 8 + 7]);
  }
}
__device__ __forceinline__ float dot64(const float* qf, const u16* krow) {
  const uint4* kp = (const uint4*)krow;
  float s = 0.f;
#pragma unroll
  for (int c = 0; c < 8; ++c) {
    uint4 u = kp[c];
    float a0, a1, a2, a3, a4, a5, a6, a7;
    up2(u.x, a0, a1); up2(u.y, a2, a3); up2(u.z, a4, a5); up2(u.w, a6, a7);
    s += qf[c * 8 + 0] * a0 + qf[c * 8 + 1] * a1 + qf[c * 8 + 2] * a2 + qf[c * 8 + 3] * a3
       + qf[c * 8 + 4] * a4 + qf[c * 8 + 5] * a5 + qf[c * 8 + 6] * a6 + qf[c * 8 + 7] * a7;
  }
  return s;
}

// ---------- stage-1 attention: one query per wave ----------
__global__ __launch_bounds__(256)
void attn1_k(const u16* __restrict__ Qs, const u16* __restrict__ Ks,
             const u16* __restrict__ Vs, const u16* __restrict__ Kr,
             const u16* __restrict__ Vr, u16* __restrict__ outA)
{
  int gw = blockIdx.x * 4 + (threadIdx.x >> 6);
  int bh = gw >> 6, qi = gw & 63;
  int b = bh >> 4, h = bh & 15;
  int lane = threadIdx.x & 63;
  const u16* qB = Qs + (size_t)bh * SLEN * HDIM;
  const u16* kS = Ks + (size_t)bh * SLEN * HDIM;
  const u16* vS = Vs + (size_t)bh * SLEN * HDIM;
  const u16* kR = Kr + (size_t)bh * RLEN * HDIM;
  const u16* vR = Vr + (size_t)bh * RLEN * HDIM;

  float qf[64];
  loadq(qB + qi * HDIM, qf);
  bool v1 = (lane <= qi);
  bool v2 = (lane < 32);
  float s1 = v1 ? dot64(qf, kS + lane * HDIM) : 0.f;
  float s2 = v2 ? dot64(qf, kR + (qi * 32 + lane) * HDIM) : 0.f;
  float sc1 = v1 ? s1 * 0.125f : -1e30f;
  float sc2 = v2 ? s2 * 0.125f : -1e30f;
  float mx = fmaxf(sc1, sc2);
#pragma unroll
  for (int off = 32; off; off >>= 1) mx = fmaxf(mx, __shfl_xor(mx, off));
  float e1 = v1 ? __expf(sc1 - mx) : 0.f;
  float e2 = v2 ? __expf(sc2 - mx) : 0.f;
  float sm = e1 + e2;
#pragma unroll
  for (int off = 32; off; off >>= 1) sm += __shfl_xor(sm, off);
  float inv = 1.f / sm;

  float a0 = 0.f, a1 = 0.f, a2 = 0.f, a3 = 0.f;
  const u16* vrow = vR + (size_t)qi * 32 * HDIM + lane;
#pragma unroll
  for (int j = 0; j < 64; j += 4) {
    a0 += __shfl(e1, j + 0) * bf2f(vS[(j + 0) * HDIM + lane]);
    a1 += __shfl(e1, j + 1) * bf2f(vS[(j + 1) * HDIM + lane]);
    a2 += __shfl(e1, j + 2) * bf2f(vS[(j + 2) * HDIM + lane]);
    a3 += __shfl(e1, j + 3) * bf2f(vS[(j + 3) * HDIM + lane]);
  }
#pragma unroll
  for (int j = 0; j < 32; j += 4) {
    a0 += __shfl(e2, j + 0) * bf2f(vrow[(j + 0) * HDIM]);
    a1 += __shfl(e2, j + 1) * bf2f(vrow[(j + 1) * HDIM]);
    a2 += __shfl(e2, j + 2) * bf2f(vrow[(j + 2) * HDIM]);
    a3 += __shfl(e2, j + 3) * bf2f(vrow[(j + 3) * HDIM]);
  }
  float accv = (a0 + a1) + (a2 + a3);
  outA[((size_t)(b * SLEN + qi)) * EMBED + h * HDIM + lane] = f2bf(accv * inv);
}

// ---------- stage-2 attention: MFMA per (b,h,bar) block ----------
__global__ __launch_bounds__(256)
void attn2_k(const u16* __restrict__ Qr, const u16* __restrict__ Kr,
             const u16* __restrict__ Vr, const u16* __restrict__ Ks2,
             const u16* __restrict__ Vs2, u16* __restrict__ outA)
{
  __shared__ __align__(16) float Sf[32][104];
  __shared__ __align__(16) u16 Pb[32][104];
  __shared__ __align__(16) u16 Vt[64][104];

  int bar = blockIdx.x, bh = blockIdx.y;
  int b = bh >> 4, h = bh & 15;
  int nS = bar + 1;
  int tid = threadIdx.x, lane = tid & 63, w = tid >> 6;
  int l15 = lane & 15, lg = lane >> 4;

  const u16* qB = Qr + ((size_t)bh * RLEN + bar * 32) * HDIM;
  const u16* kS = Ks2 + (size_t)bh * SLEN * HDIM;
  const u16* kR = Kr + ((size_t)bh * RLEN + bar * 32) * HDIM;
  const u16* vS = Vs2 + (size_t)bh * SLEN * HDIM;
  const u16* vR = Vr + ((size_t)bh * RLEN + bar * 32) * HDIM;

  for (int e = tid; e < 96 * 64; e += 256) {
    int key = e >> 6, d = e & 63;
    Vt[d][key] = (key < 64) ? vS[key * 64 + d] : vR[(key - 64) * 64 + d];
  }

#pragma unroll
  for (int i = 0; i < 3; ++i) {
    int t = w * 3 + i, r = t / 6, c = t % 6;
    const u16* arow = qB + (r * 16 + l15) * 64 + lg * 8;
    const u16* brow = (c < 4) ? (kS + (c * 16 + l15) * 64 + lg * 8)
                              : (kR + ((c - 4) * 16 + l15) * 64 + lg * 8);
    f32x4 acc = {};
    acc = __builtin_amdgcn_mfma_f32_16x16x32_bf16(*(const short8*)arow,
                                                  *(const short8*)brow, acc, 0, 0, 0);
    acc = __builtin_amdgcn_mfma_f32_16x16x32_bf16(*(const short8*)(arow + 32),
                                                  *(const short8*)(brow + 32), acc, 0, 0, 0);
#pragma unroll
    for (int j = 0; j < 4; ++j)
      Sf[r * 16 + lg * 4 + j][c * 16 + l15] = acc[j] * 0.125f;
  }
  __syncthreads();

  {
    int r = w * 8 + (lane >> 3), sub = lane & 7;
    float vals[12];
    float mx = -1e30f;
#pragma unroll
    for (int j = 0; j < 12; ++j) {
      int c = sub + 8 * j;
      bool valid = (c < nS) || (c >= 64 && c < 96 && (c - 64) <= r);
      float v = valid ? Sf[r][c] : -1e30f;
      vals[j] = v;
      mx = fmaxf(mx, v);
    }
#pragma unroll
    for (int off = 1; off < 8; off <<= 1) mx = fmaxf(mx, __shfl_xor(mx, off));
    float sm = 0.f;
#pragma unroll
    for (int j = 0; j < 12; ++j) {
      vals[j] = __expf(vals[j] - mx);
      sm += vals[j];
    }
#pragma unroll
    for (int off = 1; off < 8; off <<= 1) sm += __shfl_xor(sm, off);
    float inv = 1.f / sm;
#pragma unroll
    for (int j = 0; j < 12; ++j) {
      int c = sub + 8 * j;
      Pb[r][c] = f2bf(vals[j] * inv);
    }
  }
  __syncthreads();

#pragma unroll
  for (int i = 0; i < 2; ++i) {
    int t = w * 2 + i, r = t >> 2, dc = t & 3;
    f32x4 acc = {};
#pragma unroll
    for (int ks = 0; ks < 3; ++ks) {
      short8 a = *(const short8*)&Pb[r * 16 + l15][ks * 32 + lg * 8];
      short8 bb = *(const short8*)&Vt[dc * 16 + l15][ks * 32 + lg * 8];
      acc = __builtin_amdgcn_mfma_f32_16x16x32_bf16(a, bb, acc, 0, 0, 0);
    }
    int d = dc * 16 + l15;
#pragma unroll
    for (int j = 0; j < 4; ++j) {
      int qq = r * 16 + lg * 4 + j;
      int tt = bar * 32 + qq;
      outA[((size_t)(b * RLEN + tt)) * EMBED + h * 64 + d] = f2bf(acc[j]);
    }
  }
}

// ---------- host ----------
extern "C" void kernel_launch(void* const* d_in, const int* in_sizes, int n_in,
                              void* d_out, int out_size, void* d_ws, size_t ws_size,
                              hipStream_t stream) {
  const float* sum_x = (const float*)d_in[0];
  const float* reg_x = (const float*)d_in[1];
  const float* W[10]; const float* Bv[10];
  for (int i = 0; i < 10; ++i) {
    W[i] = (const float*)d_in[4 + 2 * i];
    Bv[i] = (const float*)d_in[5 + 2 * i];
  }

  char* ws = (char*)d_ws;
  size_t off = 0;
  auto alloc = [&](size_t bytes) -> void* {
    void* p = ws + off;
    off += (bytes + 255) & ~(size_t)255;
    return p;
  };

  const size_t SX = (size_t)NBATCH * SLEN * EMBED;
  const size_t RX = (size_t)NBATCH * RLEN * EMBED;

  float* cosT = (float*)alloc((size_t)TOTKV * 32 * 4);
  float* sinT = (float*)alloc((size_t)TOTKV * 32 * 4);
  u16* sxb = (u16*)alloc(SX * 2);
  u16* rxb = (u16*)alloc(RX * 2);
  u16* Wt  = (u16*)alloc((size_t)10 * EMBED * EMBED * 2);
  u16* Qs = (u16*)alloc(SX * 2);
  u16* Ks = (u16*)alloc(SX * 2);
  u16* Vs = (u16*)alloc(SX * 2);
  u16* Qr = (u16*)alloc(RX * 2);
  u16* Kr = (u16*)alloc(RX * 2);
  u16* Vr = (u16*)alloc(RX * 2);
  u16* sattn = (u16*)alloc(SX * 2);
  u16* Ks2 = (u16*)alloc(SX * 2);
  u16* Vs2 = (u16*)alloc(SX * 2);
  u16* rattn = (u16*)alloc(RX * 2);
  (void)ws_size; (void)in_sizes; (void)n_in; (void)out_size;

  rope_table_k<<<(TOTKV * 32 + 255) / 256, 256, 0, stream>>>(cosT, sinT);
  f2bf_k<<<(int)(SX / 4 + 255) / 256, 256, 0, stream>>>(sum_x, sxb, (int)SX);
  f2bf_k<<<(int)(RX / 4 + 255) / 256, 256, 0, stream>>>(reg_x, rxb, (int)RX);
  WSrc wsrc;
  for (int i = 0; i < 10; ++i) wsrc.p[i] = W[i];
  transpose_w_k<<<dim3(16, 16, 10), 256, 0, stream>>>(wsrc, Wt);

  B10 biases;
  for (int i = 0; i < 10; ++i) biases.p[i] = Bv[i];

#define WT(i) (Wt + (size_t)(i) * EMBED * EMBED)
  // fused sum+reg QKV GEMM (+RoPE on q,k)
  qkv_gemm_k<<<dim3(8, 33, 3), 256, 0, stream>>>(rxb, sxb, Wt, biases,
      Qs, Ks, Vs, Qr, Kr, Vr, cosT, sinT);
  // stage-1 attention -> sattn
  attn1_k<<<512, 256, 0, stream>>>(Qs, Ks, Vs, Kr, Vr, sattn);
  // fused k2/v2 projections + summary out-projection
  float* outS = (float*)d_out;
  float* outR = outS + SX;
  gemm_k<<<dim3(8, 1, 3), 256, 0, stream>>>(sattn, WT(8), WT(9), WT(3),
      Bv[8], Bv[9], Bv[3], Ks2, Vs2, outS, SLEN, 1, 1, 2, 0, cosT, sinT);
  // stage-2 attention -> rattn
  attn2_k<<<dim3(64, 32), 256, 0, stream>>>(Qr, Kr, Vr, Ks2, Vs2, rattn);
  // regular out-projection -> d_out (128x64 tiles, 512 blocks)
  gemm64_k<<<dim3(16, 32), 256, 0, stream>>>(rattn, WT(7), Bv[7], outR);
#undef WT
}